// Round 7
// baseline (2133.070 us; speedup 1.0000x reference)
//
#include <hip/hip_runtime.h>
#include <hip/hip_bf16.h>
#include <math.h>

typedef __attribute__((ext_vector_type(8))) short short8;
typedef __attribute__((ext_vector_type(4))) float f32x4;
typedef unsigned short ushort_t;
typedef unsigned int uint_t;

typedef __attribute__((address_space(1))) const void gvoid_t;
typedef __attribute__((address_space(3))) void lvoid_t;

#define VTILES 250

static __device__ __forceinline__ ushort_t f2b(float f){
  __hip_bfloat16 h = __float2bfloat16(f);
  return *reinterpret_cast<ushort_t*>(&h);
}
static __device__ __forceinline__ float b2f(ushort_t u){
  __hip_bfloat16 h = *reinterpret_cast<__hip_bfloat16*>(&u);
  return __bfloat162float(h);
}
static __device__ __forceinline__ float sigmoidf_(float x){ return 1.0f/(1.0f+__expf(-x)); }

// ---------- transpose + f32->bf16 convert: dst[c][dcoloff + r] = src[r][c] ----------
__global__ void k_transpose_cvt(const float* __restrict__ src, ushort_t* __restrict__ dst,
                                int C, int dstride, int dcoloff) {
  __shared__ ushort_t tile[64][72];
  int cb = blockIdx.x * 64, rb = blockIdx.y * 64;
  int tid = threadIdx.x;
  for (int it = 0; it < 4; ++it) {
    int e = tid + it*256;
    int row = e >> 4;
    int seg = e & 15;
    float4 v = *reinterpret_cast<const float4*>(&src[(size_t)(rb+row)*C + cb + seg*4]);
    tile[seg*4+0][row] = f2b(v.x);
    tile[seg*4+1][row] = f2b(v.y);
    tile[seg*4+2][row] = f2b(v.z);
    tile[seg*4+3][row] = f2b(v.w);
  }
  __syncthreads();
  for (int it = 0; it < 2; ++it) {
    int e = tid + it*256;
    int cl = e >> 3;
    int seg = e & 7;
    uint4 v = *reinterpret_cast<uint4*>(&tile[cl][seg*8]);
    *reinterpret_cast<uint4*>(&dst[(size_t)(cb+cl)*dstride + dcoloff + rb + seg*8]) = v;
  }
}

// ---------- features [n][d][16] f32 -> fBT [(n*16+p)][d] bf16 ----------
__global__ void k_featT(const float* __restrict__ feat, ushort_t* __restrict__ fBT) {
  __shared__ ushort_t t[16][264];
  int n = blockIdx.x;
  int tid = threadIdx.x;
  for (int it = 0; it < 4; ++it) {
    int d = it*256 + tid;
    const float* src = &feat[((size_t)n*1024 + d)*16];
    #pragma unroll
    for (int q = 0; q < 4; ++q) {
      float4 v = *reinterpret_cast<const float4*>(&src[q*4]);
      t[q*4+0][tid] = f2b(v.x);
      t[q*4+1][tid] = f2b(v.y);
      t[q*4+2][tid] = f2b(v.z);
      t[q*4+3][tid] = f2b(v.w);
    }
    __syncthreads();
    #pragma unroll
    for (int w = 0; w < 2; ++w) {
      int e = tid + w*256;
      int p = e >> 5;
      int seg = e & 31;
      uint4 v = *reinterpret_cast<uint4*>(&t[p][seg*8]);
      *reinterpret_cast<uint4*>(&fBT[((size_t)n*16 + p)*1024 + it*256 + seg*8]) = v;
    }
    __syncthreads();
  }
}

// ---------- embedding gather -> bf16 ----------
__global__ void k_embed(const int* __restrict__ captions, const float* __restrict__ W_embed,
                        ushort_t* __restrict__ xb) {
  int e = (blockIdx.x*256 + threadIdx.x) * 4;
  int nt = e >> 9;
  int n = nt >> 5, t = nt & 31;
  int col = e & 511;
  int tok = captions[n*33 + t];
  float4 v = *reinterpret_cast<const float4*>(&W_embed[(size_t)tok*512 + col]);
  ushort4 o; o.x=f2b(v.x); o.y=f2b(v.y); o.z=f2b(v.z); o.w=f2b(v.w);
  *reinterpret_cast<ushort4*>(&xb[e]) = o;
}

// ---------- A_flat/Abt = WprojT @ fBT^T + b_proj ; h0 fused (MFMA GEMM) ----------
__global__ void k_projmm(const ushort_t* __restrict__ WprojT, const ushort_t* __restrict__ fBT,
                         const float* __restrict__ b_proj, float* __restrict__ A_flat,
                         ushort_t* __restrict__ Abt, float* __restrict__ hbuf) {
  __shared__ ushort_t As[64*64];
  __shared__ ushort_t Bs[64*64];
  int kt = blockIdx.x, nt = blockIdx.y;
  int k0 = kt*64, n0 = nt*64;
  int tid = threadIdx.x;
  int wave = tid>>6, lane = tid&63, lr = lane&15, lg = lane>>4;
  int srow = lane>>3, sxor8 = ((lane&7)^srow)*8;
  f32x4 acc[4];
  #pragma unroll
  for (int nf=0;nf<4;++nf) acc[nf] = (f32x4){0.f,0.f,0.f,0.f};
  for (int kc = 0; kc < 1024; kc += 64){
    __syncthreads();
    #pragma unroll
    for (int u = 0; u < 2; ++u){
      int r0 = wave*16 + u*8;
      const ushort_t* srcA = &WprojT[(size_t)(k0 + r0 + srow)*1024 + kc + sxor8];
      const ushort_t* srcB = &fBT[(size_t)(n0 + r0 + srow)*1024 + kc + sxor8];
      __builtin_amdgcn_global_load_lds((gvoid_t*)srcA, (lvoid_t*)&As[r0*64], 16, 0, 0);
      __builtin_amdgcn_global_load_lds((gvoid_t*)srcB, (lvoid_t*)&Bs[r0*64], 16, 0, 0);
    }
    __syncthreads();
    #pragma unroll
    for (int kk = 0; kk < 2; ++kk){
      int swz = (((kk*4 + lg) ^ (lr & 7)) * 8);
      short8 af = *reinterpret_cast<short8*>(&As[(wave*16 + lr)*64 + swz]);
      #pragma unroll
      for (int nf = 0; nf < 4; ++nf){
        short8 bf = *reinterpret_cast<short8*>(&Bs[(nf*16 + lr)*64 + swz]);
        acc[nf] = __builtin_amdgcn_mfma_f32_16x16x32_bf16(af, bf, acc[nf], 0, 0, 0);
      }
    }
  }
  #pragma unroll
  for (int nf=0;nf<4;++nf){
    int ncol = n0 + nf*16 + lr;
    int nidx = ncol >> 4, p = ncol & 15;
    ushort4 ab;
    #pragma unroll
    for (int r=0;r<4;++r){
      int kh = k0 + wave*16 + lg*4 + r;
      float val = acc[nf][r] + b_proj[kh];
      A_flat[((size_t)nidx*1024 + kh)*16 + p] = val;
      (&ab.x)[r] = f2b(val);
      float s = val;
      s += __shfl_xor(s, 1, 64);
      s += __shfl_xor(s, 2, 64);
      s += __shfl_xor(s, 4, 64);
      s += __shfl_xor(s, 8, 64);
      if (lr == 0) hbuf[(nt*4 + nf)*1024 + kh] = s * (1.f/16.f);
    }
    *reinterpret_cast<ushort4*>(&Abt[(size_t)ncol*1024 + k0 + wave*16 + lg*4]) = ab;
  }
}

// ---------- P3[n][j][p] = sum_k Wattn[k][j] * A_flat[n][k][p]  (MFMA GEMM) ----------
__global__ void k_pmm(const ushort_t* __restrict__ WcatT, const ushort_t* __restrict__ Abt,
                      ushort_t* __restrict__ P3) {
  __shared__ ushort_t As[64*64];
  __shared__ ushort_t Bs[64*64];
  __shared__ ushort_t Dt2[64][72];
  int jt = blockIdx.x, nt = blockIdx.y;
  int j0 = jt*64, n0 = nt*64;
  int tid = threadIdx.x;
  int wave = tid>>6, lane = tid&63, lr = lane&15, lg = lane>>4;
  int srow = lane>>3, sxor8 = ((lane&7)^srow)*8;
  f32x4 acc[4];
  #pragma unroll
  for (int nf=0;nf<4;++nf) acc[nf] = (f32x4){0.f,0.f,0.f,0.f};
  for (int kc = 0; kc < 1024; kc += 64){
    __syncthreads();
    #pragma unroll
    for (int u = 0; u < 2; ++u){
      int r0 = wave*16 + u*8;
      const ushort_t* srcA = &WcatT[(size_t)(j0 + r0 + srow)*2560 + 1536 + kc + sxor8];
      const ushort_t* srcB = &Abt[(size_t)(n0 + r0 + srow)*1024 + kc + sxor8];
      __builtin_amdgcn_global_load_lds((gvoid_t*)srcA, (lvoid_t*)&As[r0*64], 16, 0, 0);
      __builtin_amdgcn_global_load_lds((gvoid_t*)srcB, (lvoid_t*)&Bs[r0*64], 16, 0, 0);
    }
    __syncthreads();
    #pragma unroll
    for (int kk = 0; kk < 2; ++kk){
      int swz = (((kk*4 + lg) ^ (lr & 7)) * 8);
      short8 af = *reinterpret_cast<short8*>(&As[(wave*16 + lr)*64 + swz]);
      #pragma unroll
      for (int nf = 0; nf < 4; ++nf){
        short8 bf = *reinterpret_cast<short8*>(&Bs[(nf*16 + lr)*64 + swz]);
        acc[nf] = __builtin_amdgcn_mfma_f32_16x16x32_bf16(af, bf, acc[nf], 0, 0, 0);
      }
    }
  }
  __syncthreads();
  #pragma unroll
  for (int nf=0;nf<4;++nf)
    #pragma unroll
    for (int r=0;r<4;++r)
      Dt2[wave*16 + lg*4 + r][nf*16 + lr] = f2b(acc[nf][r]);
  __syncthreads();
  #pragma unroll
  for (int it=0; it<2; ++it){
    int e = it*256 + tid;
    int row = e >> 3, seg = e & 7;
    uint4 v = *reinterpret_cast<uint4*>(&Dt2[row][seg*8]);
    *reinterpret_cast<uint4*>(&P3[(((size_t)nt*4 + (seg>>1))*4096 + j0 + row)*16 + (seg&1)*8]) = v;
  }
}

// ---------- xpre[nt][j] = xb @ Wx ----------
__global__ void k_xmm(const ushort_t* __restrict__ WcatT, const ushort_t* __restrict__ xb,
                      ushort_t* __restrict__ xpre) {
  __shared__ ushort_t As[64*64];
  __shared__ ushort_t Bs[64*64];
  __shared__ float Dt[64][68];
  int jt = blockIdx.x, mt = blockIdx.y;
  int j0 = jt*64, m0 = mt*64;
  int tid = threadIdx.x;
  int wave = tid>>6, lane = tid&63, lr = lane&15, lg = lane>>4;
  int srow = lane>>3, sxor8 = ((lane&7)^srow)*8;
  f32x4 acc[4];
  #pragma unroll
  for (int nf=0;nf<4;++nf) acc[nf] = (f32x4){0.f,0.f,0.f,0.f};
  for (int kc = 0; kc < 512; kc += 64){
    __syncthreads();
    #pragma unroll
    for (int u = 0; u < 2; ++u){
      int r0 = wave*16 + u*8;
      const ushort_t* srcA = &WcatT[(size_t)(j0 + r0 + srow)*2560 + kc + sxor8];
      const ushort_t* srcB = &xb[(size_t)(m0 + r0 + srow)*512 + kc + sxor8];
      __builtin_amdgcn_global_load_lds((gvoid_t*)srcA, (lvoid_t*)&As[r0*64], 16, 0, 0);
      __builtin_amdgcn_global_load_lds((gvoid_t*)srcB, (lvoid_t*)&Bs[r0*64], 16, 0, 0);
    }
    __syncthreads();
    #pragma unroll
    for (int kk = 0; kk < 2; ++kk){
      int swz = (((kk*4 + lg) ^ (lr & 7)) * 8);
      short8 af = *reinterpret_cast<short8*>(&As[(wave*16 + lr)*64 + swz]);
      #pragma unroll
      for (int nf = 0; nf < 4; ++nf){
        short8 bf = *reinterpret_cast<short8*>(&Bs[(nf*16 + lr)*64 + swz]);
        acc[nf] = __builtin_amdgcn_mfma_f32_16x16x32_bf16(af, bf, acc[nf], 0, 0, 0);
      }
    }
  }
  __syncthreads();
  #pragma unroll
  for (int nf=0; nf<4; ++nf)
    #pragma unroll
    for (int r=0;r<4;++r)
      Dt[nf*16+lr][wave*16 + lg*4 + r] = acc[nf][r];
  __syncthreads();
  #pragma unroll
  for (int it=0; it<4; ++it){
    int e = tid + it*256;
    int nrow = e >> 4, seg = e & 15;
    float4 v = *reinterpret_cast<float4*>(&Dt[nrow][seg*4]);
    ushort4 o; o.x=f2b(v.x); o.y=f2b(v.y); o.z=f2b(v.z); o.w=f2b(v.w);
    *reinterpret_cast<ushort4*>(&xpre[(size_t)(m0+nrow)*4096 + j0 + seg*4]) = o;
  }
}

// ---------- fused per-step kernel: gate role (blocks 0..255) + mm role (256..767) ----------
// Gate blocks release hbf via 256 distributed monotonic flags; mm blocks prefetch the
// Wh slice into LDS before waiting, then stage hbf and run the MFMA.
__global__ void __launch_bounds__(256, 4)
k_step(int i, const ushort_t* __restrict__ xpre, float* __restrict__ a_part,
       const float* __restrict__ bvec, const ushort_t* __restrict__ P3,
       const float* __restrict__ A_flat, const float* __restrict__ hbuf,
       float* __restrict__ cbuf, const float* __restrict__ sp_rd,
       float* __restrict__ sp_wr, ushort_t* __restrict__ hbf,
       ushort_t* __restrict__ hall, const ushort_t* __restrict__ WcatT,
       uint_t* __restrict__ done) {
  __shared__ char smem[32768];
  __shared__ float wvLds[16];
  __shared__ float wred[4][16];
  int b = blockIdx.x;
  int tid = threadIdx.x;
  int wave = tid>>6, lane = tid&63;
  int srow = lane>>3, sxor8 = ((lane&7)^srow)*8;

  if (b < 256) {
    // ================= gate role =================
    int n = b >> 2, sp = b & 3;
    int k = sp*256 + tid;
    float hv;
    if (i == 0){
      hv = hbuf[n*1024 + k];
      cbuf[n*1024 + k] = hv;
      hbf[n*1024 + k] = f2b(hv);
    } else {
      if (tid < 16){
        float sv = (sp_rd[(n*4+0)*16+tid] + sp_rd[(n*4+1)*16+tid] +
                    sp_rd[(n*4+2)*16+tid] + sp_rd[(n*4+3)*16+tid]) * (1.f/32.f);
        float m = sv;
        #pragma unroll
        for (int d=1; d<16; d<<=1) m = fmaxf(m, __shfl_xor(m, d, 64));
        float e = __expf(sv - m);
        float s = e;
        #pragma unroll
        for (int d=1; d<16; d<<=1) s += __shfl_xor(s, d, 64);
        wvLds[tid] = e / s;
      }
      __syncthreads();
      float wv[16];
      #pragma unroll
      for (int p=0;p<16;++p) wv[p] = wvLds[p];
      float av[4];
      #pragma unroll
      for (int g=0;g<4;++g){
        int j = g*1024 + k;
        float x = bvec[j] + b2f(xpre[(size_t)(n*32 + (i-1))*4096 + j]);
        #pragma unroll
        for (int ks=0;ks<8;++ks) x += a_part[((size_t)ks*64 + n)*4096 + j];
        const ushort_t* pp = &P3[((size_t)n*4096 + j)*16];
        short8 p0 = *reinterpret_cast<const short8*>(pp);
        short8 p1 = *reinterpret_cast<const short8*>(pp+8);
        #pragma unroll
        for (int p=0;p<8;++p) x += wv[p]*b2f((ushort_t)p0[p]);
        #pragma unroll
        for (int p=0;p<8;++p) x += wv[8+p]*b2f((ushort_t)p1[p]);
        av[g]=x;
      }
      float ig=sigmoidf_(av[0]), fg=sigmoidf_(av[1]), og=sigmoidf_(av[2]), gg=tanhf(av[3]);
      float c = fg*cbuf[n*1024+k] + ig*gg;
      hv = og*tanhf(c);
      cbuf[n*1024+k] = c;
      hall[((size_t)n*32 + (i-1))*1024 + k] = f2b(hv);
      if (i < 32) hbf[n*1024+k] = f2b(hv);
    }
    if (i < 32){
      __syncthreads();              // drains this block's hbf stores (vmcnt before barrier)
      if (tid == 0){
        __threadfence();            // write back XCD L2 -> device visibility
        __hip_atomic_store(&done[b], (uint_t)(i+1), __ATOMIC_RELEASE, __HIP_MEMORY_SCOPE_AGENT);
      }
    }
    if (i == 32) return;
    // score partials for next step's softmax
    float sacc[16];
    const float* An = &A_flat[((size_t)n*1024 + k)*16];
    #pragma unroll
    for (int p=0;p<16;p+=4){
      float4 a4 = *reinterpret_cast<const float4*>(&An[p]);
      sacc[p] = hv*a4.x; sacc[p+1] = hv*a4.y; sacc[p+2] = hv*a4.z; sacc[p+3] = hv*a4.w;
    }
    #pragma unroll
    for (int d=1; d<64; d<<=1)
      #pragma unroll
      for (int p=0;p<16;++p) sacc[p] += __shfl_xor(sacc[p], d, 64);
    if (lane == 0)
      #pragma unroll
      for (int p=0;p<16;++p) wred[wave][p] = sacc[p];
    __syncthreads();
    if (tid < 16)
      sp_wr[(n*4+sp)*16 + tid] = wred[0][tid]+wred[1][tid]+wred[2][tid]+wred[3][tid];
  } else {
    // ================= mm role: a_part[ks] = h @ Wh (K-chunk of 128) =================
    ushort_t* AsL = reinterpret_cast<ushort_t*>(smem);          // [2][64][64]
    ushort_t* BsL = reinterpret_cast<ushort_t*>(smem + 16384);  // [2][64][64]
    int idx = b - 256;
    int jt = idx & 63, ks = idx >> 6;
    int j0 = jt*64;
    // stage Wh slice (h-independent) while gates compute
    #pragma unroll
    for (int c = 0; c < 2; ++c)
      #pragma unroll
      for (int u = 0; u < 2; ++u){
        int r0 = wave*16 + u*8;
        const ushort_t* srcA = &WcatT[(size_t)(j0 + r0 + srow)*2560 + 512 + ks*128 + c*64 + sxor8];
        __builtin_amdgcn_global_load_lds((gvoid_t*)srcA, (lvoid_t*)&AsL[(c*64 + r0)*64], 16, 0, 0);
      }
    // wait for all 256 gate blocks (distributed flags, monotonic values)
    if (wave == 0){
      const uint_t tgt = (uint_t)(i+1);
      for (;;){
        bool ok = true;
        #pragma unroll
        for (int q=0;q<4;++q){
          uint_t v = __hip_atomic_load(&done[lane*4+q], __ATOMIC_RELAXED, __HIP_MEMORY_SCOPE_AGENT);
          ok &= (v >= tgt);
        }
        if (__all(ok)) break;
        __builtin_amdgcn_s_sleep(1);
      }
    }
    __syncthreads();
    __threadfence();   // invalidate stale hbf lines in this XCD's L2
    #pragma unroll
    for (int c = 0; c < 2; ++c)
      #pragma unroll
      for (int u = 0; u < 2; ++u){
        int r0 = wave*16 + u*8;
        const ushort_t* srcB = &hbf[(size_t)(r0 + srow)*1024 + ks*128 + c*64 + sxor8];
        __builtin_amdgcn_global_load_lds((gvoid_t*)srcB, (lvoid_t*)&BsL[(c*64 + r0)*64], 16, 0, 0);
      }
    int lr = lane & 15, lg = lane >> 4;
    f32x4 acc[4];
    #pragma unroll
    for (int nf=0;nf<4;++nf) acc[nf] = (f32x4){0.f,0.f,0.f,0.f};
    __syncthreads();
    #pragma unroll
    for (int c = 0; c < 2; ++c)
      #pragma unroll
      for (int kk = 0; kk < 2; ++kk){
        int swz = (((kk*4 + lg) ^ (lr & 7)) * 8);
        short8 af = *reinterpret_cast<short8*>(&AsL[(c*64 + wave*16 + lr)*64 + swz]);
        #pragma unroll
        for (int nf = 0; nf < 4; ++nf){
          short8 bf = *reinterpret_cast<short8*>(&BsL[(c*64 + nf*16 + lr)*64 + swz]);
          acc[nf] = __builtin_amdgcn_mfma_f32_16x16x32_bf16(af, bf, acc[nf], 0, 0, 0);
        }
      }
    __syncthreads();
    float (*Dt)[68] = reinterpret_cast<float(*)[68]>(smem);
    #pragma unroll
    for (int nf=0; nf<4; ++nf)
      #pragma unroll
      for (int r=0;r<4;++r)
        Dt[nf*16+lr][wave*16 + lg*4 + r] = acc[nf][r];
    __syncthreads();
    #pragma unroll
    for (int it=0; it<4; ++it){
      int e = tid + it*256;
      int nrow = e >> 4, seg = e & 15;
      float4 v = *reinterpret_cast<float4*>(&Dt[nrow][seg*4]);
      *reinterpret_cast<float4*>(&a_part[((size_t)ks*64 + nrow)*4096 + j0 + seg*4]) = v;
    }
  }
}

// ---------- scores tile + fused partial logsumexp over 128-v tile ----------
__global__ void __launch_bounds__(256, 4)
k_score(const ushort_t* __restrict__ WoutT, const ushort_t* __restrict__ hall,
        const float* __restrict__ b_out,
        float* __restrict__ pmax, float* __restrict__ psum) {
  __shared__ ushort_t As[128*64];
  __shared__ ushort_t Bs[128*64];
  __shared__ float bLds[128];
  __shared__ float pmLds[4][128];
  __shared__ float psLds[4][128];
  int bid = blockIdx.x;
  int wg = (bid & 7) * 500 + (bid >> 3);
  int vb = wg >> 4, rb = wg & 15;
  int v0 = vb * 128, r0 = rb * 128;
  int tid = threadIdx.x;
  int wave = tid >> 6, lane = tid & 63, lr = lane & 15, lg = lane >> 4;
  if (tid < 128) bLds[tid] = b_out[v0 + tid];

  int srow = lane >> 3;
  int sxor = ((lane & 7) ^ srow) << 3;

  f32x4 acc[2][8];
  #pragma unroll
  for (int a=0;a<2;++a)
    #pragma unroll
    for (int q=0;q<8;++q) acc[a][q]=(f32x4){0.f,0.f,0.f,0.f};

  for (int kc = 0; kc < 1024; kc += 64) {
    __syncthreads();
    #pragma unroll
    for (int i = 0; i < 4; ++i) {
      int rowg = (wave*4 + i) * 8;
      const ushort_t* gsA = &WoutT[(size_t)(v0 + rowg + srow)*1024 + kc + sxor];
      const ushort_t* gsB = &hall [(size_t)(r0 + rowg + srow)*1024 + kc + sxor];
      __builtin_amdgcn_global_load_lds((gvoid_t*)gsA, (lvoid_t*)&As[rowg*64], 16, 0, 0);
      __builtin_amdgcn_global_load_lds((gvoid_t*)gsB, (lvoid_t*)&Bs[rowg*64], 16, 0, 0);
    }
    __syncthreads();
    #pragma unroll
    for (int kk = 0; kk < 2; ++kk) {
      int swz = ((kk*4 + lg) ^ (lr & 7)) << 3;
      int rowA = wave*32 + lr;
      short8 af0 = *reinterpret_cast<short8*>(&As[rowA*64 + swz]);
      short8 af1 = *reinterpret_cast<short8*>(&As[(rowA+16)*64 + swz]);
      #pragma unroll
      for (int nr = 0; nr < 8; ++nr) {
        short8 bf = *reinterpret_cast<short8*>(&Bs[(nr*16+lr)*64 + swz]);
        acc[0][nr] = __builtin_amdgcn_mfma_f32_16x16x32_bf16(af0, bf, acc[0][nr], 0,0,0);
        acc[1][nr] = __builtin_amdgcn_mfma_f32_16x16x32_bf16(af1, bf, acc[1][nr], 0,0,0);
      }
    }
  }
  #pragma unroll
  for (int nr=0;nr<8;++nr){
    float m = -1e30f;
    float xv[8];
    #pragma unroll
    for (int mv=0;mv<2;++mv)
      #pragma unroll
      for (int r=0;r<4;++r){
        float x = acc[mv][nr][r] + bLds[wave*32 + mv*16 + lg*4 + r];
        xv[mv*4+r]=x; m = fmaxf(m,x);
      }
    float s=0.f;
    #pragma unroll
    for (int i=0;i<8;++i) s += __expf(xv[i]-m);
    #pragma unroll
    for (int d=16; d<=32; d<<=1){
      float om = __shfl_xor(m, d, 64);
      float os = __shfl_xor(s, d, 64);
      float nm = fmaxf(m, om);
      s = s*__expf(m-nm) + os*__expf(om-nm);
      m = nm;
    }
    if (lg == 0){
      pmLds[wave][nr*16+lr] = m;
      psLds[wave][nr*16+lr] = s;
    }
  }
  __syncthreads();
  if (tid < 128){
    float m=-1e30f;
    #pragma unroll
    for (int w=0;w<4;++w) m = fmaxf(m, pmLds[w][tid]);
    float s=0.f;
    #pragma unroll
    for (int w=0;w<4;++w) s += psLds[w][tid]*__expf(pmLds[w][tid]-m);
    pmax[(size_t)(r0+tid)*VTILES + vb] = m;
    psum[(size_t)(r0+tid)*VTILES + vb] = s;
  }
}

// ---------- target score + lse combine -> per-row masked nll (merged) ----------
__global__ void k_nll(const ushort_t* __restrict__ hall, const ushort_t* __restrict__ WoutT,
                      const float* __restrict__ b_out, const int* __restrict__ captions,
                      const float* __restrict__ pmax, const float* __restrict__ psum,
                      float* __restrict__ row_loss) {
  int tid = threadIdx.x;
  int wave = tid>>6, lane = tid&63;
  int r = blockIdx.x*4 + wave;
  int n = r>>5, t = r&31;
  int y = captions[n*33 + t + 1];
  const ushort_t* hrow = hall + (size_t)r*1024;
  const ushort_t* wrow = WoutT + (size_t)y*1024;
  float dot = 0.f;
  #pragma unroll
  for (int i=0;i<2;++i){
    int off = lane*8 + i*512;
    short8 hv = *reinterpret_cast<const short8*>(&hrow[off]);
    short8 wv = *reinterpret_cast<const short8*>(&wrow[off]);
    #pragma unroll
    for (int e2=0;e2<8;++e2) dot += b2f((ushort_t)hv[e2])*b2f((ushort_t)wv[e2]);
  }
  float m = -1e30f, s = 0.f;
  for (int j = lane; j < VTILES; j += 64){
    float mj = pmax[(size_t)r*VTILES + j];
    float sj = psum[(size_t)r*VTILES + j];
    float nm = fmaxf(m, mj);
    s = s*__expf(m-nm) + sj*__expf(mj-nm);
    m = nm;
  }
  #pragma unroll
  for (int d=32; d>=1; d>>=1){
    dot += __shfl_xor(dot, d, 64);
    float om = __shfl_xor(m, d, 64);
    float os = __shfl_xor(s, d, 64);
    float nm = fmaxf(m, om);
    s = s*__expf(m-nm) + os*__expf(om-nm);
    m = nm;
  }
  if (lane==0){
    float lse = m + __logf(s);
    row_loss[r] = (y != 0) ? (lse - (dot + b_out[y])) : 0.f;
  }
}

// ---------- final deterministic sum ----------
__global__ void k_final(const float* __restrict__ row_loss, float* __restrict__ out) {
  __shared__ float red[256];
  int tid = threadIdx.x;
  float s = 0.f;
  #pragma unroll
  for (int i=0;i<8;++i) s += row_loss[tid + i*256];
  red[tid] = s;
  __syncthreads();
  for (int off=128; off>=1; off>>=1){
    if (tid<off) red[tid] += red[tid+off];
    __syncthreads();
  }
  if (tid==0) out[0] = red[0] * (1.f/64.f);
}

extern "C" void kernel_launch(void* const* d_in, const int* in_sizes, int n_in,
                              void* d_out, int out_size, void* d_ws, size_t ws_size,
                              hipStream_t stream) {
  const float* features = (const float*)d_in[0];
  const int*   captions = (const int*)d_in[1];
  const float* W_embed  = (const float*)d_in[2];
  const float* Wx       = (const float*)d_in[3];
  const float* Wh       = (const float*)d_in[4];
  const float* Wattn    = (const float*)d_in[5];
  const float* b        = (const float*)d_in[6];
  const float* W_proj   = (const float*)d_in[7];
  const float* b_proj   = (const float*)d_in[8];
  const float* W_out    = (const float*)d_in[9];
  const float* b_out    = (const float*)d_in[10];
  float* out = (float*)d_out;

  char* wsp = (char*)d_ws;
  size_t off = 0;
  auto alloc = [&](size_t bytes)->char*{
    char* p = wsp + off; off += (bytes + 255) & ~(size_t)255; return p;
  };
  ushort_t* WcatT  = (ushort_t*)alloc((size_t)4096*2560*2);
  ushort_t* WoutT  = (ushort_t*)alloc((size_t)32000*1024*2);
  ushort_t* WprojT = (ushort_t*)alloc((size_t)1024*1024*2);
  ushort_t* fBT    = (ushort_t*)alloc((size_t)1024*1024*2);
  ushort_t* Abt    = (ushort_t*)alloc((size_t)1024*1024*2);
  float* A_flat    = (float*)alloc((size_t)64*1024*16*4);
  ushort_t* xb     = (ushort_t*)alloc((size_t)64*32*512*2);
  float* hbuf      = (float*)alloc((size_t)64*1024*4);
  ushort_t* P3     = (ushort_t*)alloc((size_t)64*4096*16*2);
  ushort_t* xpre   = (ushort_t*)alloc((size_t)2048*4096*2);
  float* a_part    = (float*)alloc((size_t)8*64*4096*4);
  ushort_t* hbf    = (ushort_t*)alloc((size_t)64*1024*2);
  float* cbuf      = (float*)alloc((size_t)64*1024*4);
  float* spbuf     = (float*)alloc((size_t)2*64*4*16*4);
  ushort_t* hall   = (ushort_t*)alloc((size_t)2048*1024*2);
  float* pmax      = (float*)alloc((size_t)2048*250*4);
  float* psum      = (float*)alloc((size_t)2048*250*4);
  float* row_loss  = (float*)alloc((size_t)2048*4);
  uint_t* done     = (uint_t*)alloc((size_t)256*4);

  hipMemsetAsync(done, 0, 256*4, stream);

  hipLaunchKernelGGL(k_transpose_cvt, dim3(64, 8),   dim3(256), 0, stream, Wx,     WcatT,  4096, 2560, 0);
  hipLaunchKernelGGL(k_transpose_cvt, dim3(64, 16),  dim3(256), 0, stream, Wh,     WcatT,  4096, 2560, 512);
  hipLaunchKernelGGL(k_transpose_cvt, dim3(64, 16),  dim3(256), 0, stream, Wattn,  WcatT,  4096, 2560, 1536);
  hipLaunchKernelGGL(k_transpose_cvt, dim3(500, 16), dim3(256), 0, stream, W_out,  WoutT,  32000, 1024, 0);
  hipLaunchKernelGGL(k_transpose_cvt, dim3(16, 16),  dim3(256), 0, stream, W_proj, WprojT, 1024, 1024, 0);
  hipLaunchKernelGGL(k_featT, dim3(64), dim3(256), 0, stream, features, fBT);
  hipLaunchKernelGGL(k_embed, dim3(1024), dim3(256), 0, stream, captions, W_embed, xb);
  hipLaunchKernelGGL(k_projmm, dim3(16, 16), dim3(256), 0, stream, WprojT, fBT, b_proj, A_flat, Abt, hbuf);
  hipLaunchKernelGGL(k_pmm, dim3(64, 16), dim3(256), 0, stream, WcatT, Abt, P3);
  hipLaunchKernelGGL(k_xmm, dim3(64, 32), dim3(256), 0, stream, WcatT, xb, xpre);

  for (int i = 0; i <= 32; ++i){
    const float* sp_rd = spbuf + ((i+1)&1)*4096;
    float*       sp_wr = spbuf + (i&1)*4096;
    hipLaunchKernelGGL(k_step, dim3(i < 32 ? 768 : 256), dim3(256), 0, stream,
                       i, xpre, a_part, b, P3, A_flat, hbuf, cbuf, sp_rd, sp_wr,
                       hbf, hall, WcatT, done);
  }

  hipLaunchKernelGGL(k_score, dim3(4000), dim3(256), 0, stream, WoutT, hall, b_out, pmax, psum);
  hipLaunchKernelGGL(k_nll, dim3(512), dim3(256), 0, stream, hall, WoutT, b_out, captions, pmax, psum, row_loss);
  hipLaunchKernelGGL(k_final, dim3(1), dim3(256), 0, stream, row_loss, out);
}

// Round 8
// 673.837 us; speedup vs baseline: 3.1656x; 3.1656x over previous
//
#include <hip/hip_runtime.h>
#include <hip/hip_bf16.h>
#include <math.h>

typedef __attribute__((ext_vector_type(8))) short short8;
typedef __attribute__((ext_vector_type(4))) float f32x4;
typedef unsigned short ushort_t;
typedef unsigned int uint_t;

typedef __attribute__((address_space(1))) const void gvoid_t;
typedef __attribute__((address_space(3))) void lvoid_t;

#define VTILES 125

static __device__ __forceinline__ ushort_t f2b(float f){
  __hip_bfloat16 h = __float2bfloat16(f);
  return *reinterpret_cast<ushort_t*>(&h);
}
static __device__ __forceinline__ float b2f(ushort_t u){
  __hip_bfloat16 h = *reinterpret_cast<__hip_bfloat16*>(&u);
  return __bfloat162float(h);
}
static __device__ __forceinline__ float sigmoidf_(float x){ return 1.0f/(1.0f+__expf(-x)); }

// ---------- transpose + f32->bf16 convert: dst[c][dcoloff + r] = src[r][c] ----------
__global__ void k_transpose_cvt(const float* __restrict__ src, ushort_t* __restrict__ dst,
                                int C, int dstride, int dcoloff) {
  __shared__ ushort_t tile[64][72];
  int cb = blockIdx.x * 64, rb = blockIdx.y * 64;
  int tid = threadIdx.x;
  for (int it = 0; it < 4; ++it) {
    int e = tid + it*256;
    int row = e >> 4;
    int seg = e & 15;
    float4 v = *reinterpret_cast<const float4*>(&src[(size_t)(rb+row)*C + cb + seg*4]);
    tile[seg*4+0][row] = f2b(v.x);
    tile[seg*4+1][row] = f2b(v.y);
    tile[seg*4+2][row] = f2b(v.z);
    tile[seg*4+3][row] = f2b(v.w);
  }
  __syncthreads();
  for (int it = 0; it < 2; ++it) {
    int e = tid + it*256;
    int cl = e >> 3;
    int seg = e & 7;
    uint4 v = *reinterpret_cast<uint4*>(&tile[cl][seg*8]);
    *reinterpret_cast<uint4*>(&dst[(size_t)(cb+cl)*dstride + dcoloff + rb + seg*8]) = v;
  }
}

// ---------- features [n][d][16] f32 -> fBT [(n*16+p)][d] bf16 ----------
__global__ void k_featT(const float* __restrict__ feat, ushort_t* __restrict__ fBT) {
  __shared__ ushort_t t[16][264];
  int n = blockIdx.x;
  int tid = threadIdx.x;
  for (int it = 0; it < 4; ++it) {
    int d = it*256 + tid;
    const float* src = &feat[((size_t)n*1024 + d)*16];
    #pragma unroll
    for (int q = 0; q < 4; ++q) {
      float4 v = *reinterpret_cast<const float4*>(&src[q*4]);
      t[q*4+0][tid] = f2b(v.x);
      t[q*4+1][tid] = f2b(v.y);
      t[q*4+2][tid] = f2b(v.z);
      t[q*4+3][tid] = f2b(v.w);
    }
    __syncthreads();
    #pragma unroll
    for (int w = 0; w < 2; ++w) {
      int e = tid + w*256;
      int p = e >> 5;
      int seg = e & 31;
      uint4 v = *reinterpret_cast<uint4*>(&t[p][seg*8]);
      *reinterpret_cast<uint4*>(&fBT[((size_t)n*16 + p)*1024 + it*256 + seg*8]) = v;
    }
    __syncthreads();
  }
}

// ---------- embedding gather -> bf16 ----------
__global__ void k_embed(const int* __restrict__ captions, const float* __restrict__ W_embed,
                        ushort_t* __restrict__ xb) {
  int e = (blockIdx.x*256 + threadIdx.x) * 4;
  int nt = e >> 9;
  int n = nt >> 5, t = nt & 31;
  int col = e & 511;
  int tok = captions[n*33 + t];
  float4 v = *reinterpret_cast<const float4*>(&W_embed[(size_t)tok*512 + col]);
  ushort4 o; o.x=f2b(v.x); o.y=f2b(v.y); o.z=f2b(v.z); o.w=f2b(v.w);
  *reinterpret_cast<ushort4*>(&xb[e]) = o;
}

// ---------- A_flat/Abt = WprojT @ fBT^T + b_proj ; h0 fused (MFMA GEMM) ----------
__global__ void k_projmm(const ushort_t* __restrict__ WprojT, const ushort_t* __restrict__ fBT,
                         const float* __restrict__ b_proj, float* __restrict__ A_flat,
                         ushort_t* __restrict__ Abt, float* __restrict__ hbuf) {
  __shared__ ushort_t As[64*64];
  __shared__ ushort_t Bs[64*64];
  int kt = blockIdx.x, nt = blockIdx.y;
  int k0 = kt*64, n0 = nt*64;
  int tid = threadIdx.x;
  int wave = tid>>6, lane = tid&63, lr = lane&15, lg = lane>>4;
  int srow = lane>>3, sxor8 = ((lane&7)^srow)*8;
  f32x4 acc[4];
  #pragma unroll
  for (int nf=0;nf<4;++nf) acc[nf] = (f32x4){0.f,0.f,0.f,0.f};
  for (int kc = 0; kc < 1024; kc += 64){
    __syncthreads();
    #pragma unroll
    for (int u = 0; u < 2; ++u){
      int r0 = wave*16 + u*8;
      const ushort_t* srcA = &WprojT[(size_t)(k0 + r0 + srow)*1024 + kc + sxor8];
      const ushort_t* srcB = &fBT[(size_t)(n0 + r0 + srow)*1024 + kc + sxor8];
      __builtin_amdgcn_global_load_lds((gvoid_t*)srcA, (lvoid_t*)&As[r0*64], 16, 0, 0);
      __builtin_amdgcn_global_load_lds((gvoid_t*)srcB, (lvoid_t*)&Bs[r0*64], 16, 0, 0);
    }
    __syncthreads();
    #pragma unroll
    for (int kk = 0; kk < 2; ++kk){
      int swz = (((kk*4 + lg) ^ (lr & 7)) * 8);
      short8 af = *reinterpret_cast<short8*>(&As[(wave*16 + lr)*64 + swz]);
      #pragma unroll
      for (int nf = 0; nf < 4; ++nf){
        short8 bf = *reinterpret_cast<short8*>(&Bs[(nf*16 + lr)*64 + swz]);
        acc[nf] = __builtin_amdgcn_mfma_f32_16x16x32_bf16(af, bf, acc[nf], 0, 0, 0);
      }
    }
  }
  #pragma unroll
  for (int nf=0;nf<4;++nf){
    int ncol = n0 + nf*16 + lr;
    int nidx = ncol >> 4, p = ncol & 15;
    ushort4 ab;
    #pragma unroll
    for (int r=0;r<4;++r){
      int kh = k0 + wave*16 + lg*4 + r;
      float val = acc[nf][r] + b_proj[kh];
      A_flat[((size_t)nidx*1024 + kh)*16 + p] = val;
      (&ab.x)[r] = f2b(val);
      float s = val;
      s += __shfl_xor(s, 1, 64);
      s += __shfl_xor(s, 2, 64);
      s += __shfl_xor(s, 4, 64);
      s += __shfl_xor(s, 8, 64);
      if (lr == 0) hbuf[(nt*4 + nf)*1024 + kh] = s * (1.f/16.f);
    }
    *reinterpret_cast<ushort4*>(&Abt[(size_t)ncol*1024 + k0 + wave*16 + lg*4]) = ab;
  }
}

// ---------- P3[n][j][p] = sum_k Wattn[k][j] * A_flat[n][k][p]  (MFMA GEMM) ----------
__global__ void k_pmm(const ushort_t* __restrict__ WcatT, const ushort_t* __restrict__ Abt,
                      ushort_t* __restrict__ P3) {
  __shared__ ushort_t As[64*64];
  __shared__ ushort_t Bs[64*64];
  __shared__ ushort_t Dt2[64][72];
  int jt = blockIdx.x, nt = blockIdx.y;
  int j0 = jt*64, n0 = nt*64;
  int tid = threadIdx.x;
  int wave = tid>>6, lane = tid&63, lr = lane&15, lg = lane>>4;
  int srow = lane>>3, sxor8 = ((lane&7)^srow)*8;
  f32x4 acc[4];
  #pragma unroll
  for (int nf=0;nf<4;++nf) acc[nf] = (f32x4){0.f,0.f,0.f,0.f};
  for (int kc = 0; kc < 1024; kc += 64){
    __syncthreads();
    #pragma unroll
    for (int u = 0; u < 2; ++u){
      int r0 = wave*16 + u*8;
      const ushort_t* srcA = &WcatT[(size_t)(j0 + r0 + srow)*2560 + 1536 + kc + sxor8];
      const ushort_t* srcB = &Abt[(size_t)(n0 + r0 + srow)*1024 + kc + sxor8];
      __builtin_amdgcn_global_load_lds((gvoid_t*)srcA, (lvoid_t*)&As[r0*64], 16, 0, 0);
      __builtin_amdgcn_global_load_lds((gvoid_t*)srcB, (lvoid_t*)&Bs[r0*64], 16, 0, 0);
    }
    __syncthreads();
    #pragma unroll
    for (int kk = 0; kk < 2; ++kk){
      int swz = (((kk*4 + lg) ^ (lr & 7)) * 8);
      short8 af = *reinterpret_cast<short8*>(&As[(wave*16 + lr)*64 + swz]);
      #pragma unroll
      for (int nf = 0; nf < 4; ++nf){
        short8 bf = *reinterpret_cast<short8*>(&Bs[(nf*16 + lr)*64 + swz]);
        acc[nf] = __builtin_amdgcn_mfma_f32_16x16x32_bf16(af, bf, acc[nf], 0, 0, 0);
      }
    }
  }
  __syncthreads();
  #pragma unroll
  for (int nf=0;nf<4;++nf)
    #pragma unroll
    for (int r=0;r<4;++r)
      Dt2[wave*16 + lg*4 + r][nf*16 + lr] = f2b(acc[nf][r]);
  __syncthreads();
  #pragma unroll
  for (int it=0; it<2; ++it){
    int e = it*256 + tid;
    int row = e >> 3, seg = e & 7;
    uint4 v = *reinterpret_cast<uint4*>(&Dt2[row][seg*8]);
    *reinterpret_cast<uint4*>(&P3[(((size_t)nt*4 + (seg>>1))*4096 + j0 + row)*16 + (seg&1)*8]) = v;
  }
}

// ---------- xpre[nt][j] = xb @ Wx ----------
__global__ void k_xmm(const ushort_t* __restrict__ WcatT, const ushort_t* __restrict__ xb,
                      ushort_t* __restrict__ xpre) {
  __shared__ ushort_t As[64*64];
  __shared__ ushort_t Bs[64*64];
  __shared__ float Dt[64][68];
  int jt = blockIdx.x, mt = blockIdx.y;
  int j0 = jt*64, m0 = mt*64;
  int tid = threadIdx.x;
  int wave = tid>>6, lane = tid&63, lr = lane&15, lg = lane>>4;
  int srow = lane>>3, sxor8 = ((lane&7)^srow)*8;
  f32x4 acc[4];
  #pragma unroll
  for (int nf=0;nf<4;++nf) acc[nf] = (f32x4){0.f,0.f,0.f,0.f};
  for (int kc = 0; kc < 512; kc += 64){
    __syncthreads();
    #pragma unroll
    for (int u = 0; u < 2; ++u){
      int r0 = wave*16 + u*8;
      const ushort_t* srcA = &WcatT[(size_t)(j0 + r0 + srow)*2560 + kc + sxor8];
      const ushort_t* srcB = &xb[(size_t)(m0 + r0 + srow)*512 + kc + sxor8];
      __builtin_amdgcn_global_load_lds((gvoid_t*)srcA, (lvoid_t*)&As[r0*64], 16, 0, 0);
      __builtin_amdgcn_global_load_lds((gvoid_t*)srcB, (lvoid_t*)&Bs[r0*64], 16, 0, 0);
    }
    __syncthreads();
    #pragma unroll
    for (int kk = 0; kk < 2; ++kk){
      int swz = (((kk*4 + lg) ^ (lr & 7)) * 8);
      short8 af = *reinterpret_cast<short8*>(&As[(wave*16 + lr)*64 + swz]);
      #pragma unroll
      for (int nf = 0; nf < 4; ++nf){
        short8 bf = *reinterpret_cast<short8*>(&Bs[(nf*16 + lr)*64 + swz]);
        acc[nf] = __builtin_amdgcn_mfma_f32_16x16x32_bf16(af, bf, acc[nf], 0, 0, 0);
      }
    }
  }
  __syncthreads();
  #pragma unroll
  for (int nf=0; nf<4; ++nf)
    #pragma unroll
    for (int r=0;r<4;++r)
      Dt[nf*16+lr][wave*16 + lg*4 + r] = acc[nf][r];
  __syncthreads();
  #pragma unroll
  for (int it=0; it<4; ++it){
    int e = tid + it*256;
    int nrow = e >> 4, seg = e & 15;
    float4 v = *reinterpret_cast<float4*>(&Dt[nrow][seg*4]);
    ushort4 o; o.x=f2b(v.x); o.y=f2b(v.y); o.z=f2b(v.z); o.w=f2b(v.w);
    *reinterpret_cast<ushort4*>(&xpre[(size_t)(m0+nrow)*4096 + j0 + seg*4]) = o;
  }
}

// ---------- per-step gates + c/h update + score partials (256 blocks) ----------
__global__ void k_gate(int i, const ushort_t* __restrict__ xpre, const float* __restrict__ a_part,
                       const float* __restrict__ bvec, const ushort_t* __restrict__ P3,
                       const float* __restrict__ A_flat, const float* __restrict__ hbuf,
                       float* __restrict__ cbuf, const float* __restrict__ sp_rd,
                       float* __restrict__ sp_wr, ushort_t* __restrict__ hbf,
                       ushort_t* __restrict__ hall) {
  __shared__ float wvLds[16];
  __shared__ float wred[4][16];
  int n = blockIdx.x >> 2, sp = blockIdx.x & 3;
  int tid = threadIdx.x;
  int wave = tid>>6, lane = tid&63;
  int k = sp*256 + tid;
  float hv;
  if (i == 0){
    hv = hbuf[n*1024 + k];
    cbuf[n*1024 + k] = hv;
    hbf[n*1024 + k] = f2b(hv);
  } else {
    if (tid < 16){
      float sv = (sp_rd[(n*4+0)*16+tid] + sp_rd[(n*4+1)*16+tid] +
                  sp_rd[(n*4+2)*16+tid] + sp_rd[(n*4+3)*16+tid]) * (1.f/32.f);
      float m = sv;
      #pragma unroll
      for (int d=1; d<16; d<<=1) m = fmaxf(m, __shfl_xor(m, d, 64));
      float e = __expf(sv - m);
      float s = e;
      #pragma unroll
      for (int d=1; d<16; d<<=1) s += __shfl_xor(s, d, 64);
      wvLds[tid] = e / s;
    }
    __syncthreads();
    float wv[16];
    #pragma unroll
    for (int p=0;p<16;++p) wv[p] = wvLds[p];
    float av[4];
    #pragma unroll
    for (int g=0;g<4;++g){
      int j = g*1024 + k;
      float x = bvec[j] + b2f(xpre[(size_t)(n*32 + (i-1))*4096 + j]);
      #pragma unroll
      for (int ks=0;ks<8;++ks) x += a_part[((size_t)ks*64 + n)*4096 + j];
      const ushort_t* pp = &P3[((size_t)n*4096 + j)*16];
      short8 p0 = *reinterpret_cast<const short8*>(pp);
      short8 p1 = *reinterpret_cast<const short8*>(pp+8);
      #pragma unroll
      for (int p=0;p<8;++p) x += wv[p]*b2f((ushort_t)p0[p]);
      #pragma unroll
      for (int p=0;p<8;++p) x += wv[8+p]*b2f((ushort_t)p1[p]);
      av[g]=x;
    }
    float ig=sigmoidf_(av[0]), fg=sigmoidf_(av[1]), og=sigmoidf_(av[2]), gg=tanhf(av[3]);
    float c = fg*cbuf[n*1024+k] + ig*gg;
    hv = og*tanhf(c);
    cbuf[n*1024+k] = c;
    hall[((size_t)n*32 + (i-1))*1024 + k] = f2b(hv);
    if (i < 32) hbf[n*1024+k] = f2b(hv);
  }
  if (i == 32) return;
  float sacc[16];
  const float* An = &A_flat[((size_t)n*1024 + k)*16];
  #pragma unroll
  for (int p=0;p<16;p+=4){
    float4 a4 = *reinterpret_cast<const float4*>(&An[p]);
    sacc[p] = hv*a4.x; sacc[p+1] = hv*a4.y; sacc[p+2] = hv*a4.z; sacc[p+3] = hv*a4.w;
  }
  #pragma unroll
  for (int d=1; d<64; d<<=1)
    #pragma unroll
    for (int p=0;p<16;++p) sacc[p] += __shfl_xor(sacc[p], d, 64);
  if (lane == 0)
    #pragma unroll
    for (int p=0;p<16;++p) wred[wave][p] = sacc[p];
  __syncthreads();
  if (tid < 16)
    sp_wr[(n*4+sp)*16 + tid] = wred[0][tid]+wred[1][tid]+wred[2][tid]+wred[3][tid];
}

// ---------- a_part[ks] = h @ Wh (K-chunk ks of 128; 512 blocks) ----------
__global__ void k_mm(const ushort_t* __restrict__ WcatT, const ushort_t* __restrict__ hbf,
                     float* __restrict__ a_part) {
  __shared__ ushort_t As[64*64];
  __shared__ ushort_t Bs[64*64];
  __shared__ float Dt[64][68];
  int jt = blockIdx.x, ks = blockIdx.y;
  int j0 = jt*64;
  int tid = threadIdx.x;
  int wave = tid>>6, lane = tid&63, lr = lane&15, lg = lane>>4;
  int srow = lane>>3, sxor8 = ((lane&7)^srow)*8;
  f32x4 acc[4];
  #pragma unroll
  for (int nf=0;nf<4;++nf) acc[nf] = (f32x4){0.f,0.f,0.f,0.f};
  for (int kc = 0; kc < 128; kc += 64){
    __syncthreads();
    #pragma unroll
    for (int u = 0; u < 2; ++u){
      int r0 = wave*16 + u*8;
      const ushort_t* srcA = &WcatT[(size_t)(j0 + r0 + srow)*2560 + 512 + ks*128 + kc + sxor8];
      const ushort_t* srcB = &hbf[(size_t)(r0 + srow)*1024 + ks*128 + kc + sxor8];
      __builtin_amdgcn_global_load_lds((gvoid_t*)srcA, (lvoid_t*)&As[r0*64], 16, 0, 0);
      __builtin_amdgcn_global_load_lds((gvoid_t*)srcB, (lvoid_t*)&Bs[r0*64], 16, 0, 0);
    }
    __syncthreads();
    #pragma unroll
    for (int kk = 0; kk < 2; ++kk){
      int swz = (((kk*4 + lg) ^ (lr & 7)) * 8);
      short8 af = *reinterpret_cast<short8*>(&As[(wave*16 + lr)*64 + swz]);
      #pragma unroll
      for (int nf = 0; nf < 4; ++nf){
        short8 bf = *reinterpret_cast<short8*>(&Bs[(nf*16 + lr)*64 + swz]);
        acc[nf] = __builtin_amdgcn_mfma_f32_16x16x32_bf16(af, bf, acc[nf], 0, 0, 0);
      }
    }
  }
  __syncthreads();
  #pragma unroll
  for (int nf=0; nf<4; ++nf)
    #pragma unroll
    for (int r=0;r<4;++r)
      Dt[nf*16+lr][wave*16 + lg*4 + r] = acc[nf][r];
  __syncthreads();
  #pragma unroll
  for (int it=0; it<4; ++it){
    int e = tid + it*256;
    int nrow = e >> 4, seg = e & 15;
    float4 v = *reinterpret_cast<float4*>(&Dt[nrow][seg*4]);
    *reinterpret_cast<float4*>(&a_part[((size_t)ks*64 + nrow)*4096 + j0 + seg*4]) = v;
  }
}

// ---------- 8-phase-style deep-pipelined scores + fused partial logsumexp ----------
// 256v x 128r tile, BK=64, 3-set rotating LDS, counted vmcnt(6), raw barriers, setprio.
__global__ void __launch_bounds__(512, 2)
k_score(const ushort_t* __restrict__ WoutT, const ushort_t* __restrict__ hall,
        const float* __restrict__ b_out,
        float* __restrict__ pmax, float* __restrict__ psum) {
  __shared__ ushort_t A_lds[3][16384];   // [set][256 rows x 64 cols swizzled]
  __shared__ ushort_t B_lds[3][8192];    // [set][128 rows x 64 cols swizzled]
  __shared__ float bLds[256];
  __shared__ float pmLds[2][128];
  __shared__ float psLds[2][128];

  int bid = blockIdx.x;
  int wg = (bid & 7) * 250 + (bid >> 3);   // 2000 = 8 x 250, bijective XCD swizzle
  int vb = wg >> 4, rb = wg & 15;
  size_t v0 = (size_t)vb * 256, r0 = (size_t)rb * 128;
  int tid = threadIdx.x;
  int wid = tid >> 6, lane = tid & 63;
  int wr = wid >> 2, wc = wid & 3;         // wave: v-half (128 rows), r-quarter (32 cols)
  int lr = lane & 15, lg = lane >> 4;
  int srow = lane >> 3, sxor8 = ((lane & 7) ^ srow) * 8;

  const ushort_t* Abase = WoutT + v0*1024 + (size_t)srow*1024 + sxor8;
  const ushort_t* Bbase = hall  + r0*1024 + (size_t)srow*1024 + sxor8;

  // one staging instruction covers 64 rows (8 waves x 8 rows x 16B/lane)
  auto stA = [&](int set, int u, int t){
    __builtin_amdgcn_global_load_lds(
      (gvoid_t*)(Abase + (size_t)(u*64 + wid*8)*1024 + t*64),
      (lvoid_t*)&A_lds[set][(u*64 + wid*8)*64], 16, 0, 0);
  };
  auto stB = [&](int set, int u, int t){
    __builtin_amdgcn_global_load_lds(
      (gvoid_t*)(Bbase + (size_t)(u*64 + wid*8)*1024 + t*64),
      (lvoid_t*)&B_lds[set][(u*64 + wid*8)*64], 16, 0, 0);
  };

  f32x4 acc[8][2];
  #pragma unroll
  for (int fi=0; fi<8; ++fi)
    #pragma unroll
    for (int fj=0; fj<2; ++fj) acc[fi][fj] = (f32x4){0.f,0.f,0.f,0.f};

  short8 afr[4][2], bfr[2][2];
  auto ldA = [&](int set, int qv){
    #pragma unroll
    for (int f=0; f<4; ++f)
      #pragma unroll
      for (int kk=0; kk<2; ++kk){
        int row = wr*128 + (qv*4+f)*16 + lr;
        afr[f][kk] = *reinterpret_cast<short8*>(&A_lds[set][row*64 + (((kk*4+lg)^(lr&7))*8)]);
      }
  };
  auto ldB = [&](int set){
    #pragma unroll
    for (int fj=0; fj<2; ++fj)
      #pragma unroll
      for (int kk=0; kk<2; ++kk){
        int row = wc*32 + fj*16 + lr;
        bfr[fj][kk] = *reinterpret_cast<short8*>(&B_lds[set][row*64 + (((kk*4+lg)^(lr&7))*8)]);
      }
  };
  auto mfma16 = [&](int qv){
    __builtin_amdgcn_s_setprio(1);
    #pragma unroll
    for (int f=0; f<4; ++f)
      #pragma unroll
      for (int fj=0; fj<2; ++fj)
        #pragma unroll
        for (int kk=0; kk<2; ++kk)
          acc[qv*4+f][fj] = __builtin_amdgcn_mfma_f32_16x16x32_bf16(
              afr[f][kk], bfr[fj][kk], acc[qv*4+f][fj], 0, 0, 0);
    __builtin_amdgcn_s_setprio(0);
  };

  // prologue: tile0 -> set0, tile1 -> set1 (12 staging insts); first 6 must land.
  stA(0,0,0); stA(0,1,0); stA(0,2,0); stA(0,3,0); stB(0,0,0); stB(0,1,0);
  stA(1,0,1); stA(1,1,1); stA(1,2,1); stA(1,3,1); stB(1,0,1); stB(1,1,1);
  asm volatile("s_waitcnt vmcnt(6)" ::: "memory");
  __builtin_amdgcn_s_barrier();
  __builtin_amdgcn_sched_barrier(0);

  for (int g = 0; g < 16; ++g){
    int s = g % 3, sn = (g + 2) % 3;
    int tn = g + 2;
    bool st = tn < 16;
    // ---- phase 0: quadrant qv0 ----
    ldA(s, 0); ldB(s);
    if (st){ stA(sn,0,tn); stA(sn,1,tn); stA(sn,2,tn); }
    __builtin_amdgcn_sched_barrier(0);
    __builtin_amdgcn_s_barrier();
    __builtin_amdgcn_sched_barrier(0);
    mfma16(0);
    __builtin_amdgcn_sched_barrier(0);
    __builtin_amdgcn_s_barrier();
    __builtin_amdgcn_sched_barrier(0);
    // ---- phase 1: quadrant qv1 (B frags kept in regs) ----
    ldA(s, 1);
    if (st){ stA(sn,3,tn); stB(sn,0,tn); stB(sn,1,tn); }
    if (g == 14)      { asm volatile("s_waitcnt vmcnt(0)" ::: "memory"); }
    else if (g < 14)  { asm volatile("s_waitcnt vmcnt(6)" ::: "memory"); }
    __builtin_amdgcn_sched_barrier(0);
    __builtin_amdgcn_s_barrier();
    __builtin_amdgcn_sched_barrier(0);
    mfma16(1);
    __builtin_amdgcn_sched_barrier(0);
    __builtin_amdgcn_s_barrier();
    __builtin_amdgcn_sched_barrier(0);
  }

  // ---- epilogue: bias + partial logsumexp over the 256-v tile ----
  if (tid < 256) bLds[tid] = b_out[v0 + tid];
  __syncthreads();
  float pm_[2], ps_[2];
  #pragma unroll
  for (int fj=0; fj<2; ++fj){
    float m = -1e30f;
    #pragma unroll
    for (int fi=0; fi<8; ++fi)
      #pragma unroll
      for (int rr=0; rr<4; ++rr){
        float x = acc[fi][fj][rr] + bLds[wr*128 + fi*16 + lg*4 + rr];
        m = fmaxf(m, x);
      }
    float ssum = 0.f;
    #pragma unroll
    for (int fi=0; fi<8; ++fi)
      #pragma unroll
      for (int rr=0; rr<4; ++rr){
        float x = acc[fi][fj][rr] + bLds[wr*128 + fi*16 + lg*4 + rr];
        ssum += __expf(x - m);
      }
    #pragma unroll
    for (int d=16; d<=32; d<<=1){
      float om = __shfl_xor(m, d, 64);
      float os = __shfl_xor(ssum, d, 64);
      float nm = fmaxf(m, om);
      ssum = ssum*__expf(m-nm) + os*__expf(om-nm);
      m = nm;
    }
    pm_[fj] = m; ps_[fj] = ssum;
  }
  if (lg == 0){
    #pragma unroll
    for (int fj=0; fj<2; ++fj){
      pmLds[wr][wc*32 + fj*16 + lr] = pm_[fj];
      psLds[wr][wc*32 + fj*16 + lr] = ps_[fj];
    }
  }
  __syncthreads();
  if (tid < 128){
    float m0 = pmLds[0][tid], m1 = pmLds[1][tid];
    float m = fmaxf(m0, m1);
    float sv = psLds[0][tid]*__expf(m0-m) + psLds[1][tid]*__expf(m1-m);
    pmax[(size_t)(r0 + tid)*VTILES + vb] = m;
    psum[(size_t)(r0 + tid)*VTILES + vb] = sv;
  }
}

// ---------- target score + lse combine -> per-row masked nll ----------
__global__ void k_nll(const ushort_t* __restrict__ hall, const ushort_t* __restrict__ WoutT,
                      const float* __restrict__ b_out, const int* __restrict__ captions,
                      const float* __restrict__ pmax, const float* __restrict__ psum,
                      float* __restrict__ row_loss) {
  int tid = threadIdx.x;
  int wave = tid>>6, lane = tid&63;
  int r = blockIdx.x*4 + wave;
  int n = r>>5, t = r&31;
  int y = captions[n*33 + t + 1];
  const ushort_t* hrow = hall + (size_t)r*1024;
  const ushort_t* wrow = WoutT + (size_t)y*1024;
  float dot = 0.f;
  #pragma unroll
  for (int i=0;i<2;++i){
    int off = lane*8 + i*512;
    short8 hv = *reinterpret_cast<const short8*>(&hrow[off]);
    short8 wv = *reinterpret_cast<const short8*>(&wrow[off]);
    #pragma unroll
    for (int e2=0;e2<8;++e2) dot += b2f((ushort_t)hv[e2])*b2f((ushort_t)wv[e2]);
  }
  float m = -1e30f, s = 0.f;
  for (int j = lane; j < VTILES; j += 64){
    float mj = pmax[(size_t)r*VTILES + j];
    float sj = psum[(size_t)r*VTILES + j];
    float nm = fmaxf(m, mj);
    s = s*__expf(m-nm) + sj*__expf(mj-nm);
    m = nm;
  }
  #pragma unroll
  for (int d=32; d>=1; d>>=1){
    dot += __shfl_xor(dot, d, 64);
    float om = __shfl_xor(m, d, 64);
    float os = __shfl_xor(s, d, 64);
    float nm = fmaxf(m, om);
    s = s*__expf(m-nm) + os*__expf(om-nm);
    m = nm;
  }
  if (lane==0){
    float lse = m + __logf(s);
    row_loss[r] = (y != 0) ? (lse - (dot + b_out[y])) : 0.f;
  }
}

// ---------- final deterministic sum ----------
__global__ void k_final(const float* __restrict__ row_loss, float* __restrict__ out) {
  __shared__ float red[256];
  int tid = threadIdx.x;
  float s = 0.f;
  #pragma unroll
  for (int i=0;i<8;++i) s += row_loss[tid + i*256];
  red[tid] = s;
  __syncthreads();
  for (int off=128; off>=1; off>>=1){
    if (tid<off) red[tid] += red[tid+off];
    __syncthreads();
  }
  if (tid==0) out[0] = red[0] * (1.f/64.f);
}

extern "C" void kernel_launch(void* const* d_in, const int* in_sizes, int n_in,
                              void* d_out, int out_size, void* d_ws, size_t ws_size,
                              hipStream_t stream) {
  const float* features = (const float*)d_in[0];
  const int*   captions = (const int*)d_in[1];
  const float* W_embed  = (const float*)d_in[2];
  const float* Wx       = (const float*)d_in[3];
  const float* Wh       = (const float*)d_in[4];
  const float* Wattn    = (const float*)d_in[5];
  const float* b        = (const float*)d_in[6];
  const float* W_proj   = (const float*)d_in[7];
  const float* b_proj   = (const float*)d_in[8];
  const float* W_out    = (const float*)d_in[9];
  const float* b_out    = (const float*)d_in[10];
  float* out = (float*)d_out;

  char* wsp = (char*)d_ws;
  size_t off = 0;
  auto alloc = [&](size_t bytes)->char*{
    char* p = wsp + off; off += (bytes + 255) & ~(size_t)255; return p;
  };
  ushort_t* WcatT  = (ushort_t*)alloc((size_t)4096*2560*2);
  ushort_t* WoutT  = (ushort_t*)alloc((size_t)32000*1024*2);
  ushort_t* WprojT = (ushort_t*)alloc((size_t)1024*1024*2);
  ushort_t* fBT    = (ushort_t*)alloc((size_t)1024*1024*2);
  ushort_t* Abt    = (ushort_t*)alloc((size_t)1024*1024*2);
  float* A_flat    = (float*)alloc((size_t)64*1024*16*4);
  ushort_t* xb     = (ushort_t*)alloc((size_t)64*32*512*2);
  float* hbuf      = (float*)alloc((size_t)64*1024*4);
  ushort_t* P3     = (ushort_t*)alloc((size_t)64*4096*16*2);
  ushort_t* xpre   = (ushort_t*)alloc((size_t)2048*4096*2);
  float* a_part    = (float*)alloc((size_t)8*64*4096*4);
  ushort_t* hbf    = (ushort_t*)alloc((size_t)64*1024*2);
  float* cbuf      = (float*)alloc((size_t)64*1024*4);
  float* spbuf     = (float*)alloc((size_t)2*64*4*16*4);
  ushort_t* hall   = (ushort_t*)alloc((size_t)2048*1024*2);
  float* pmax      = (float*)alloc((size_t)2048*VTILES*4);
  float* psum      = (float*)alloc((size_t)2048*VTILES*4);
  float* row_loss  = (float*)alloc((size_t)2048*4);

  hipLaunchKernelGGL(k_transpose_cvt, dim3(64, 8),   dim3(256), 0, stream, Wx,     WcatT,  4096, 2560, 0);
  hipLaunchKernelGGL(k_transpose_cvt, dim3(64, 16),  dim3(256), 0, stream, Wh,     WcatT,  4096, 2560, 512);
  hipLaunchKernelGGL(k_transpose_cvt, dim3(64, 16),  dim3(256), 0, stream, Wattn,  WcatT,  4096, 2560, 1536);
  hipLaunchKernelGGL(k_transpose_cvt, dim3(500, 16), dim3(256), 0, stream, W_out,  WoutT,  32000, 1024, 0);
  hipLaunchKernelGGL(k_transpose_cvt, dim3(16, 16),  dim3(256), 0, stream, W_proj, WprojT, 1024, 1024, 0);
  hipLaunchKernelGGL(k_featT, dim3(64), dim3(256), 0, stream, features, fBT);
  hipLaunchKernelGGL(k_embed, dim3(1024), dim3(256), 0, stream, captions, W_embed, xb);
  hipLaunchKernelGGL(k_projmm, dim3(16, 16), dim3(256), 0, stream, WprojT, fBT, b_proj, A_flat, Abt, hbuf);
  hipLaunchKernelGGL(k_pmm, dim3(64, 16), dim3(256), 0, stream, WcatT, Abt, P3);
  hipLaunchKernelGGL(k_xmm, dim3(64, 32), dim3(256), 0, stream, WcatT, xb, xpre);

  for (int i = 0; i <= 32; ++i){
    const float* sp_rd = spbuf + ((i+1)&1)*4096;
    float*       sp_wr = spbuf + (i&1)*4096;
    hipLaunchKernelGGL(k_gate, dim3(256), dim3(256), 0, stream, i, xpre, a_part, b, P3,
                       A_flat, hbuf, cbuf, sp_rd, sp_wr, hbf, hall);
    if (i < 32)
      hipLaunchKernelGGL(k_mm, dim3(64, 8), dim3(256), 0, stream, WcatT, hbf, a_part);
  }

  hipLaunchKernelGGL(k_score, dim3(2000), dim3(512), 0, stream, WoutT, hall, b_out, pmax, psum);
  hipLaunchKernelGGL(k_nll, dim3(512), dim3(256), 0, stream, hall, WoutT, b_out, captions, pmax, psum, row_loss);
  hipLaunchKernelGGL(k_final, dim3(1), dim3(256), 0, stream, row_loss, out);
}

// Round 9
// 637.934 us; speedup vs baseline: 3.3437x; 1.0563x over previous
//
#include <hip/hip_runtime.h>
#include <hip/hip_bf16.h>
#include <math.h>

typedef __attribute__((ext_vector_type(8))) short short8;
typedef __attribute__((ext_vector_type(4))) float f32x4;
typedef unsigned short ushort_t;
typedef unsigned int uint_t;

typedef __attribute__((address_space(1))) const void gvoid_t;
typedef __attribute__((address_space(3))) void lvoid_t;

#define VTILES 125

static __device__ __forceinline__ ushort_t f2b(float f){
  __hip_bfloat16 h = __float2bfloat16(f);
  return *reinterpret_cast<ushort_t*>(&h);
}
static __device__ __forceinline__ float b2f(ushort_t u){
  __hip_bfloat16 h = *reinterpret_cast<__hip_bfloat16*>(&u);
  return __bfloat162float(h);
}
static __device__ __forceinline__ float sigmoidf_(float x){ return 1.0f/(1.0f+__expf(-x)); }

// ---------- transpose + f32->bf16 convert: dst[c][dcoloff + r] = src[r][c] ----------
__global__ void k_transpose_cvt(const float* __restrict__ src, ushort_t* __restrict__ dst,
                                int C, int dstride, int dcoloff) {
  __shared__ ushort_t tile[64][72];
  int cb = blockIdx.x * 64, rb = blockIdx.y * 64;
  int tid = threadIdx.x;
  for (int it = 0; it < 4; ++it) {
    int e = tid + it*256;
    int row = e >> 4;
    int seg = e & 15;
    float4 v = *reinterpret_cast<const float4*>(&src[(size_t)(rb+row)*C + cb + seg*4]);
    tile[seg*4+0][row] = f2b(v.x);
    tile[seg*4+1][row] = f2b(v.y);
    tile[seg*4+2][row] = f2b(v.z);
    tile[seg*4+3][row] = f2b(v.w);
  }
  __syncthreads();
  for (int it = 0; it < 2; ++it) {
    int e = tid + it*256;
    int cl = e >> 3;
    int seg = e & 7;
    uint4 v = *reinterpret_cast<uint4*>(&tile[cl][seg*8]);
    *reinterpret_cast<uint4*>(&dst[(size_t)(cb+cl)*dstride + dcoloff + rb + seg*8]) = v;
  }
}

// ---------- features [n][d][16] f32 -> fBT [(n*16+p)][d] bf16 ----------
__global__ void k_featT(const float* __restrict__ feat, ushort_t* __restrict__ fBT) {
  __shared__ ushort_t t[16][264];
  int n = blockIdx.x;
  int tid = threadIdx.x;
  for (int it = 0; it < 4; ++it) {
    int d = it*256 + tid;
    const float* src = &feat[((size_t)n*1024 + d)*16];
    #pragma unroll
    for (int q = 0; q < 4; ++q) {
      float4 v = *reinterpret_cast<const float4*>(&src[q*4]);
      t[q*4+0][tid] = f2b(v.x);
      t[q*4+1][tid] = f2b(v.y);
      t[q*4+2][tid] = f2b(v.z);
      t[q*4+3][tid] = f2b(v.w);
    }
    __syncthreads();
    #pragma unroll
    for (int w = 0; w < 2; ++w) {
      int e = tid + w*256;
      int p = e >> 5;
      int seg = e & 31;
      uint4 v = *reinterpret_cast<uint4*>(&t[p][seg*8]);
      *reinterpret_cast<uint4*>(&fBT[((size_t)n*16 + p)*1024 + it*256 + seg*8]) = v;
    }
    __syncthreads();
  }
}

// ---------- embedding gather -> bf16 ----------
__global__ void k_embed(const int* __restrict__ captions, const float* __restrict__ W_embed,
                        ushort_t* __restrict__ xb) {
  int e = (blockIdx.x*256 + threadIdx.x) * 4;
  int nt = e >> 9;
  int n = nt >> 5, t = nt & 31;
  int col = e & 511;
  int tok = captions[n*33 + t];
  float4 v = *reinterpret_cast<const float4*>(&W_embed[(size_t)tok*512 + col]);
  ushort4 o; o.x=f2b(v.x); o.y=f2b(v.y); o.z=f2b(v.z); o.w=f2b(v.w);
  *reinterpret_cast<ushort4*>(&xb[e]) = o;
}

// ---------- A_flat/Abt = WprojT @ fBT^T + b_proj ; h0 fused (MFMA GEMM) ----------
__global__ void k_projmm(const ushort_t* __restrict__ WprojT, const ushort_t* __restrict__ fBT,
                         const float* __restrict__ b_proj, float* __restrict__ A_flat,
                         ushort_t* __restrict__ Abt, float* __restrict__ hbuf) {
  __shared__ ushort_t As[64*64];
  __shared__ ushort_t Bs[64*64];
  int kt = blockIdx.x, nt = blockIdx.y;
  int k0 = kt*64, n0 = nt*64;
  int tid = threadIdx.x;
  int wave = tid>>6, lane = tid&63, lr = lane&15, lg = lane>>4;
  int srow = lane>>3, sxor8 = ((lane&7)^srow)*8;
  f32x4 acc[4];
  #pragma unroll
  for (int nf=0;nf<4;++nf) acc[nf] = (f32x4){0.f,0.f,0.f,0.f};
  for (int kc = 0; kc < 1024; kc += 64){
    __syncthreads();
    #pragma unroll
    for (int u = 0; u < 2; ++u){
      int r0 = wave*16 + u*8;
      const ushort_t* srcA = &WprojT[(size_t)(k0 + r0 + srow)*1024 + kc + sxor8];
      const ushort_t* srcB = &fBT[(size_t)(n0 + r0 + srow)*1024 + kc + sxor8];
      __builtin_amdgcn_global_load_lds((gvoid_t*)srcA, (lvoid_t*)&As[r0*64], 16, 0, 0);
      __builtin_amdgcn_global_load_lds((gvoid_t*)srcB, (lvoid_t*)&Bs[r0*64], 16, 0, 0);
    }
    __syncthreads();
    #pragma unroll
    for (int kk = 0; kk < 2; ++kk){
      int swz = (((kk*4 + lg) ^ (lr & 7)) * 8);
      short8 af = *reinterpret_cast<short8*>(&As[(wave*16 + lr)*64 + swz]);
      #pragma unroll
      for (int nf = 0; nf < 4; ++nf){
        short8 bf = *reinterpret_cast<short8*>(&Bs[(nf*16 + lr)*64 + swz]);
        acc[nf] = __builtin_amdgcn_mfma_f32_16x16x32_bf16(af, bf, acc[nf], 0, 0, 0);
      }
    }
  }
  #pragma unroll
  for (int nf=0;nf<4;++nf){
    int ncol = n0 + nf*16 + lr;
    int nidx = ncol >> 4, p = ncol & 15;
    ushort4 ab;
    #pragma unroll
    for (int r=0;r<4;++r){
      int kh = k0 + wave*16 + lg*4 + r;
      float val = acc[nf][r] + b_proj[kh];
      A_flat[((size_t)nidx*1024 + kh)*16 + p] = val;
      (&ab.x)[r] = f2b(val);
      float s = val;
      s += __shfl_xor(s, 1, 64);
      s += __shfl_xor(s, 2, 64);
      s += __shfl_xor(s, 4, 64);
      s += __shfl_xor(s, 8, 64);
      if (lr == 0) hbuf[(nt*4 + nf)*1024 + kh] = s * (1.f/16.f);
    }
    *reinterpret_cast<ushort4*>(&Abt[(size_t)ncol*1024 + k0 + wave*16 + lg*4]) = ab;
  }
}

// ---------- P3[n][j][p] = sum_k Wattn[k][j] * A_flat[n][k][p]  (MFMA GEMM) ----------
__global__ void k_pmm(const ushort_t* __restrict__ WcatT, const ushort_t* __restrict__ Abt,
                      ushort_t* __restrict__ P3) {
  __shared__ ushort_t As[64*64];
  __shared__ ushort_t Bs[64*64];
  __shared__ ushort_t Dt2[64][72];
  int jt = blockIdx.x, nt = blockIdx.y;
  int j0 = jt*64, n0 = nt*64;
  int tid = threadIdx.x;
  int wave = tid>>6, lane = tid&63, lr = lane&15, lg = lane>>4;
  int srow = lane>>3, sxor8 = ((lane&7)^srow)*8;
  f32x4 acc[4];
  #pragma unroll
  for (int nf=0;nf<4;++nf) acc[nf] = (f32x4){0.f,0.f,0.f,0.f};
  for (int kc = 0; kc < 1024; kc += 64){
    __syncthreads();
    #pragma unroll
    for (int u = 0; u < 2; ++u){
      int r0 = wave*16 + u*8;
      const ushort_t* srcA = &WcatT[(size_t)(j0 + r0 + srow)*2560 + 1536 + kc + sxor8];
      const ushort_t* srcB = &Abt[(size_t)(n0 + r0 + srow)*1024 + kc + sxor8];
      __builtin_amdgcn_global_load_lds((gvoid_t*)srcA, (lvoid_t*)&As[r0*64], 16, 0, 0);
      __builtin_amdgcn_global_load_lds((gvoid_t*)srcB, (lvoid_t*)&Bs[r0*64], 16, 0, 0);
    }
    __syncthreads();
    #pragma unroll
    for (int kk = 0; kk < 2; ++kk){
      int swz = (((kk*4 + lg) ^ (lr & 7)) * 8);
      short8 af = *reinterpret_cast<short8*>(&As[(wave*16 + lr)*64 + swz]);
      #pragma unroll
      for (int nf = 0; nf < 4; ++nf){
        short8 bf = *reinterpret_cast<short8*>(&Bs[(nf*16 + lr)*64 + swz]);
        acc[nf] = __builtin_amdgcn_mfma_f32_16x16x32_bf16(af, bf, acc[nf], 0, 0, 0);
      }
    }
  }
  __syncthreads();
  #pragma unroll
  for (int nf=0;nf<4;++nf)
    #pragma unroll
    for (int r=0;r<4;++r)
      Dt2[wave*16 + lg*4 + r][nf*16 + lr] = f2b(acc[nf][r]);
  __syncthreads();
  #pragma unroll
  for (int it=0; it<2; ++it){
    int e = it*256 + tid;
    int row = e >> 3, seg = e & 7;
    uint4 v = *reinterpret_cast<uint4*>(&Dt2[row][seg*8]);
    *reinterpret_cast<uint4*>(&P3[(((size_t)nt*4 + (seg>>1))*4096 + j0 + row)*16 + (seg&1)*8]) = v;
  }
}

// ---------- xpre[nt][j] = xb @ Wx ----------
__global__ void k_xmm(const ushort_t* __restrict__ WcatT, const ushort_t* __restrict__ xb,
                      ushort_t* __restrict__ xpre) {
  __shared__ ushort_t As[64*64];
  __shared__ ushort_t Bs[64*64];
  __shared__ float Dt[64][68];
  int jt = blockIdx.x, mt = blockIdx.y;
  int j0 = jt*64, m0 = mt*64;
  int tid = threadIdx.x;
  int wave = tid>>6, lane = tid&63, lr = lane&15, lg = lane>>4;
  int srow = lane>>3, sxor8 = ((lane&7)^srow)*8;
  f32x4 acc[4];
  #pragma unroll
  for (int nf=0;nf<4;++nf) acc[nf] = (f32x4){0.f,0.f,0.f,0.f};
  for (int kc = 0; kc < 512; kc += 64){
    __syncthreads();
    #pragma unroll
    for (int u = 0; u < 2; ++u){
      int r0 = wave*16 + u*8;
      const ushort_t* srcA = &WcatT[(size_t)(j0 + r0 + srow)*2560 + kc + sxor8];
      const ushort_t* srcB = &xb[(size_t)(m0 + r0 + srow)*512 + kc + sxor8];
      __builtin_amdgcn_global_load_lds((gvoid_t*)srcA, (lvoid_t*)&As[r0*64], 16, 0, 0);
      __builtin_amdgcn_global_load_lds((gvoid_t*)srcB, (lvoid_t*)&Bs[r0*64], 16, 0, 0);
    }
    __syncthreads();
    #pragma unroll
    for (int kk = 0; kk < 2; ++kk){
      int swz = (((kk*4 + lg) ^ (lr & 7)) * 8);
      short8 af = *reinterpret_cast<short8*>(&As[(wave*16 + lr)*64 + swz]);
      #pragma unroll
      for (int nf = 0; nf < 4; ++nf){
        short8 bf = *reinterpret_cast<short8*>(&Bs[(nf*16 + lr)*64 + swz]);
        acc[nf] = __builtin_amdgcn_mfma_f32_16x16x32_bf16(af, bf, acc[nf], 0, 0, 0);
      }
    }
  }
  __syncthreads();
  #pragma unroll
  for (int nf=0; nf<4; ++nf)
    #pragma unroll
    for (int r=0;r<4;++r)
      Dt[nf*16+lr][wave*16 + lg*4 + r] = acc[nf][r];
  __syncthreads();
  #pragma unroll
  for (int it=0; it<4; ++it){
    int e = tid + it*256;
    int nrow = e >> 4, seg = e & 15;
    float4 v = *reinterpret_cast<float4*>(&Dt[nrow][seg*4]);
    ushort4 o; o.x=f2b(v.x); o.y=f2b(v.y); o.z=f2b(v.z); o.w=f2b(v.w);
    *reinterpret_cast<ushort4*>(&xpre[(size_t)(m0+nrow)*4096 + j0 + seg*4]) = o;
  }
}

// ---------- per-step gates + c/h update + score partials (256 blocks) ----------
__global__ void k_gate(int i, const ushort_t* __restrict__ xpre, const float* __restrict__ a_part,
                       const float* __restrict__ bvec, const ushort_t* __restrict__ P3,
                       const float* __restrict__ A_flat, const float* __restrict__ hbuf,
                       float* __restrict__ cbuf, const float* __restrict__ sp_rd,
                       float* __restrict__ sp_wr, ushort_t* __restrict__ hbf,
                       ushort_t* __restrict__ hall) {
  __shared__ float wvLds[16];
  __shared__ float wred[4][16];
  int n = blockIdx.x >> 2, sp = blockIdx.x & 3;
  int tid = threadIdx.x;
  int wave = tid>>6, lane = tid&63;
  int k = sp*256 + tid;
  float hv;
  if (i == 0){
    hv = hbuf[n*1024 + k];
    cbuf[n*1024 + k] = hv;
    hbf[n*1024 + k] = f2b(hv);
  } else {
    if (tid < 16){
      float sv = (sp_rd[(n*4+0)*16+tid] + sp_rd[(n*4+1)*16+tid] +
                  sp_rd[(n*4+2)*16+tid] + sp_rd[(n*4+3)*16+tid]) * (1.f/32.f);
      float m = sv;
      #pragma unroll
      for (int d=1; d<16; d<<=1) m = fmaxf(m, __shfl_xor(m, d, 64));
      float e = __expf(sv - m);
      float s = e;
      #pragma unroll
      for (int d=1; d<16; d<<=1) s += __shfl_xor(s, d, 64);
      wvLds[tid] = e / s;
    }
    __syncthreads();
    float wv[16];
    #pragma unroll
    for (int p=0;p<16;++p) wv[p] = wvLds[p];
    float av[4];
    #pragma unroll
    for (int g=0;g<4;++g){
      int j = g*1024 + k;
      float x = bvec[j] + b2f(xpre[(size_t)(n*32 + (i-1))*4096 + j]);
      #pragma unroll
      for (int ks=0;ks<8;++ks) x += a_part[((size_t)ks*64 + n)*4096 + j];
      const ushort_t* pp = &P3[((size_t)n*4096 + j)*16];
      short8 p0 = *reinterpret_cast<const short8*>(pp);
      short8 p1 = *reinterpret_cast<const short8*>(pp+8);
      #pragma unroll
      for (int p=0;p<8;++p) x += wv[p]*b2f((ushort_t)p0[p]);
      #pragma unroll
      for (int p=0;p<8;++p) x += wv[8+p]*b2f((ushort_t)p1[p]);
      av[g]=x;
    }
    float ig=sigmoidf_(av[0]), fg=sigmoidf_(av[1]), og=sigmoidf_(av[2]), gg=tanhf(av[3]);
    float c = fg*cbuf[n*1024+k] + ig*gg;
    hv = og*tanhf(c);
    cbuf[n*1024+k] = c;
    hall[((size_t)n*32 + (i-1))*1024 + k] = f2b(hv);
    if (i < 32) hbf[n*1024+k] = f2b(hv);
  }
  if (i == 32) return;
  float sacc[16];
  const float* An = &A_flat[((size_t)n*1024 + k)*16];
  #pragma unroll
  for (int p=0;p<16;p+=4){
    float4 a4 = *reinterpret_cast<const float4*>(&An[p]);
    sacc[p] = hv*a4.x; sacc[p+1] = hv*a4.y; sacc[p+2] = hv*a4.z; sacc[p+3] = hv*a4.w;
  }
  #pragma unroll
  for (int d=1; d<64; d<<=1)
    #pragma unroll
    for (int p=0;p<16;++p) sacc[p] += __shfl_xor(sacc[p], d, 64);
  if (lane == 0)
    #pragma unroll
    for (int p=0;p<16;++p) wred[wave][p] = sacc[p];
  __syncthreads();
  if (tid < 16)
    sp_wr[(n*4+sp)*16 + tid] = wred[0][tid]+wred[1][tid]+wred[2][tid]+wred[3][tid];
}

// ---------- a_part[ks] = h @ Wh (K-chunk ks of 128; 512 blocks) ----------
__global__ void k_mm(const ushort_t* __restrict__ WcatT, const ushort_t* __restrict__ hbf,
                     float* __restrict__ a_part) {
  __shared__ ushort_t As[64*64];
  __shared__ ushort_t Bs[64*64];
  __shared__ float Dt[64][68];
  int jt = blockIdx.x, ks = blockIdx.y;
  int j0 = jt*64;
  int tid = threadIdx.x;
  int wave = tid>>6, lane = tid&63, lr = lane&15, lg = lane>>4;
  int srow = lane>>3, sxor8 = ((lane&7)^srow)*8;
  f32x4 acc[4];
  #pragma unroll
  for (int nf=0;nf<4;++nf) acc[nf] = (f32x4){0.f,0.f,0.f,0.f};
  for (int kc = 0; kc < 128; kc += 64){
    __syncthreads();
    #pragma unroll
    for (int u = 0; u < 2; ++u){
      int r0 = wave*16 + u*8;
      const ushort_t* srcA = &WcatT[(size_t)(j0 + r0 + srow)*2560 + 512 + ks*128 + kc + sxor8];
      const ushort_t* srcB = &hbf[(size_t)(r0 + srow)*1024 + ks*128 + kc + sxor8];
      __builtin_amdgcn_global_load_lds((gvoid_t*)srcA, (lvoid_t*)&As[r0*64], 16, 0, 0);
      __builtin_amdgcn_global_load_lds((gvoid_t*)srcB, (lvoid_t*)&Bs[r0*64], 16, 0, 0);
    }
    __syncthreads();
    #pragma unroll
    for (int kk = 0; kk < 2; ++kk){
      int swz = (((kk*4 + lg) ^ (lr & 7)) * 8);
      short8 af = *reinterpret_cast<short8*>(&As[(wave*16 + lr)*64 + swz]);
      #pragma unroll
      for (int nf = 0; nf < 4; ++nf){
        short8 bf = *reinterpret_cast<short8*>(&Bs[(nf*16 + lr)*64 + swz]);
        acc[nf] = __builtin_amdgcn_mfma_f32_16x16x32_bf16(af, bf, acc[nf], 0, 0, 0);
      }
    }
  }
  __syncthreads();
  #pragma unroll
  for (int nf=0; nf<4; ++nf)
    #pragma unroll
    for (int r=0;r<4;++r)
      Dt[nf*16+lr][wave*16 + lg*4 + r] = acc[nf][r];
  __syncthreads();
  #pragma unroll
  for (int it=0; it<4; ++it){
    int e = tid + it*256;
    int nrow = e >> 4, seg = e & 15;
    float4 v = *reinterpret_cast<float4*>(&Dt[nrow][seg*4]);
    *reinterpret_cast<float4*>(&a_part[((size_t)ks*64 + nrow)*4096 + j0 + seg*4]) = v;
  }
}

// ---------- scores: 256v x 128r tile, 2-phase barriers, 8 waves, fused partial lse ----------
__global__ void __launch_bounds__(512, 4)
k_score(const ushort_t* __restrict__ WoutT, const ushort_t* __restrict__ hall,
        const float* __restrict__ b_out,
        float* __restrict__ pmax, float* __restrict__ psum) {
  __shared__ ushort_t A_lds[256*64];
  __shared__ ushort_t B_lds[128*64];
  __shared__ float bLds[256];
  __shared__ float pmLds[2][128];
  __shared__ float psLds[2][128];

  int bid = blockIdx.x;
  int wg = (bid & 7) * 250 + (bid >> 3);   // 2000 = 8 x 250, bijective XCD swizzle
  int vb = wg >> 4, rb = wg & 15;
  size_t v0 = (size_t)vb * 256, r0 = (size_t)rb * 128;
  int tid = threadIdx.x;
  int wid = tid >> 6, lane = tid & 63;
  int wr = wid >> 2, wc = wid & 3;         // wave covers v-rows [wr*128,+128), r-cols [wc*32,+32)
  int lr = lane & 15, lg = lane >> 4;
  int srow = lane >> 3, sxor8 = ((lane & 7) ^ srow) * 8;

  if (tid < 256) bLds[tid] = b_out[v0 + tid];

  const ushort_t* Abase = WoutT + v0*1024 + (size_t)srow*1024 + sxor8;
  const ushort_t* Bbase = hall  + r0*1024 + (size_t)srow*1024 + sxor8;

  f32x4 acc[8][2];
  #pragma unroll
  for (int fi=0; fi<8; ++fi)
    #pragma unroll
    for (int fj=0; fj<2; ++fj) acc[fi][fj] = (f32x4){0.f,0.f,0.f,0.f};

  for (int kc = 0; kc < 1024; kc += 64) {
    __syncthreads();   // previous tile's ds_reads complete
    // stage A: 256 rows (4 insts x 64 rows), B: 128 rows (2 insts)
    #pragma unroll
    for (int u = 0; u < 4; ++u)
      __builtin_amdgcn_global_load_lds(
        (gvoid_t*)(Abase + (size_t)(u*64 + wid*8)*1024 + kc),
        (lvoid_t*)&A_lds[(u*64 + wid*8)*64], 16, 0, 0);
    #pragma unroll
    for (int u = 0; u < 2; ++u)
      __builtin_amdgcn_global_load_lds(
        (gvoid_t*)(Bbase + (size_t)(u*64 + wid*8)*1024 + kc),
        (lvoid_t*)&B_lds[(u*64 + wid*8)*64], 16, 0, 0);
    __syncthreads();   // vmcnt(0) drain: tile ready
    #pragma unroll
    for (int kk = 0; kk < 2; ++kk) {
      int swz = ((kk*4 + lg) ^ (lr & 7)) << 3;
      short8 bf0 = *reinterpret_cast<short8*>(&B_lds[(wc*32 + lr)*64 + swz]);
      short8 bf1 = *reinterpret_cast<short8*>(&B_lds[(wc*32 + 16 + lr)*64 + swz]);
      #pragma unroll
      for (int fi = 0; fi < 8; ++fi) {
        short8 af = *reinterpret_cast<short8*>(&A_lds[(wr*128 + fi*16 + lr)*64 + swz]);
        acc[fi][0] = __builtin_amdgcn_mfma_f32_16x16x32_bf16(af, bf0, acc[fi][0], 0,0,0);
        acc[fi][1] = __builtin_amdgcn_mfma_f32_16x16x32_bf16(af, bf1, acc[fi][1], 0,0,0);
      }
    }
  }

  // ---- epilogue: bias + partial logsumexp over the 256-v tile ----
  __syncthreads();
  float pm_[2], ps_[2];
  #pragma unroll
  for (int fj=0; fj<2; ++fj){
    float m = -1e30f;
    #pragma unroll
    for (int fi=0; fi<8; ++fi)
      #pragma unroll
      for (int rr=0; rr<4; ++rr){
        float x = acc[fi][fj][rr] + bLds[wr*128 + fi*16 + lg*4 + rr];
        m = fmaxf(m, x);
      }
    float ssum = 0.f;
    #pragma unroll
    for (int fi=0; fi<8; ++fi)
      #pragma unroll
      for (int rr=0; rr<4; ++rr){
        float x = acc[fi][fj][rr] + bLds[wr*128 + fi*16 + lg*4 + rr];
        ssum += __expf(x - m);
      }
    #pragma unroll
    for (int d=16; d<=32; d<<=1){
      float om = __shfl_xor(m, d, 64);
      float os = __shfl_xor(ssum, d, 64);
      float nm = fmaxf(m, om);
      ssum = ssum*__expf(m-nm) + os*__expf(om-nm);
      m = nm;
    }
    pm_[fj] = m; ps_[fj] = ssum;
  }
  if (lg == 0){
    #pragma unroll
    for (int fj=0; fj<2; ++fj){
      pmLds[wr][wc*32 + fj*16 + lr] = pm_[fj];
      psLds[wr][wc*32 + fj*16 + lr] = ps_[fj];
    }
  }
  __syncthreads();
  if (tid < 128){
    float m0 = pmLds[0][tid], m1 = pmLds[1][tid];
    float m = fmaxf(m0, m1);
    float sv = psLds[0][tid]*__expf(m0-m) + psLds[1][tid]*__expf(m1-m);
    pmax[(size_t)(r0 + tid)*VTILES + vb] = m;
    psum[(size_t)(r0 + tid)*VTILES + vb] = sv;
  }
}

// ---------- target score + lse combine -> per-row masked nll ----------
__global__ void k_nll(const ushort_t* __restrict__ hall, const ushort_t* __restrict__ WoutT,
                      const float* __restrict__ b_out, const int* __restrict__ captions,
                      const float* __restrict__ pmax, const float* __restrict__ psum,
                      float* __restrict__ row_loss) {
  int tid = threadIdx.x;
  int wave = tid>>6, lane = tid&63;
  int r = blockIdx.x*4 + wave;
  int n = r>>5, t = r&31;
  int y = captions[n*33 + t + 1];
  const ushort_t* hrow = hall + (size_t)r*1024;
  const ushort_t* wrow = WoutT + (size_t)y*1024;
  float dot = 0.f;
  #pragma unroll
  for (int i=0;i<2;++i){
    int off = lane*8 + i*512;
    short8 hv = *reinterpret_cast<const short8*>(&hrow[off]);
    short8 wv = *reinterpret_cast<const short8*>(&wrow[off]);
    #pragma unroll
    for (int e2=0;e2<8;++e2) dot += b2f((ushort_t)hv[e2])*b2f((ushort_t)wv[e2]);
  }
  float m = -1e30f, s = 0.f;
  for (int j = lane; j < VTILES; j += 64){
    float mj = pmax[(size_t)r*VTILES + j];
    float sj = psum[(size_t)r*VTILES + j];
    float nm = fmaxf(m, mj);
    s = s*__expf(m-nm) + sj*__expf(mj-nm);
    m = nm;
  }
  #pragma unroll
  for (int d=32; d>=1; d>>=1){
    dot += __shfl_xor(dot, d, 64);
    float om = __shfl_xor(m, d, 64);
    float os = __shfl_xor(s, d, 64);
    float nm = fmaxf(m, om);
    s = s*__expf(m-nm) + os*__expf(om-nm);
    m = nm;
  }
  if (lane==0){
    float lse = m + __logf(s);
    row_loss[r] = (y != 0) ? (lse - (dot + b_out[y])) : 0.f;
  }
}

// ---------- final deterministic sum ----------
__global__ void k_final(const float* __restrict__ row_loss, float* __restrict__ out) {
  __shared__ float red[256];
  int tid = threadIdx.x;
  float s = 0.f;
  #pragma unroll
  for (int i=0;i<8;++i) s += row_loss[tid + i*256];
  red[tid] = s;
  __syncthreads();
  for (int off=128; off>=1; off>>=1){
    if (tid<off) red[tid] += red[tid+off];
    __syncthreads();
  }
  if (tid==0) out[0] = red[0] * (1.f/64.f);
}

extern "C" void kernel_launch(void* const* d_in, const int* in_sizes, int n_in,
                              void* d_out, int out_size, void* d_ws, size_t ws_size,
                              hipStream_t stream) {
  const float* features = (const float*)d_in[0];
  const int*   captions = (const int*)d_in[1];
  const float* W_embed  = (const float*)d_in[2];
  const float* Wx       = (const float*)d_in[3];
  const float* Wh       = (const float*)d_in[4];
  const float* Wattn    = (const float*)d_in[5];
  const float* b        = (const float*)d_in[6];
  const float* W_proj   = (const float*)d_in[7];
  const float* b_proj   = (const float*)d_in[8];
  const float* W_out    = (const float*)d_in[9];
  const float* b_out    = (const float*)d_in[10];
  float* out = (float*)d_out;

  char* wsp = (char*)d_ws;
  size_t off = 0;
  auto alloc = [&](size_t bytes)->char*{
    char* p = wsp + off; off += (bytes + 255) & ~(size_t)255; return p;
  };
  ushort_t* WcatT  = (ushort_t*)alloc((size_t)4096*2560*2);
  ushort_t* WoutT  = (ushort_t*)alloc((size_t)32000*1024*2);
  ushort_t* WprojT = (ushort_t*)alloc((size_t)1024*1024*2);
  ushort_t* fBT    = (ushort_t*)alloc((size_t)1024*1024*2);
  ushort_t* Abt    = (ushort_t*)alloc((size_t)1024*1024*2);
  float* A_flat    = (float*)alloc((size_t)64*1024*16*4);
  ushort_t* xb     = (ushort_t*)alloc((size_t)64*32*512*2);
  float* hbuf      = (float*)alloc((size_t)64*1024*4);
  ushort_t* P3     = (ushort_t*)alloc((size_t)64*4096*16*2);
  ushort_t* xpre   = (ushort_t*)alloc((size_t)2048*4096*2);
  float* a_part    = (float*)alloc((size_t)8*64*4096*4);
  ushort_t* hbf    = (ushort_t*)alloc((size_t)64*1024*2);
  float* cbuf      = (float*)alloc((size_t)64*1024*4);
  float* spbuf     = (float*)alloc((size_t)2*64*4*16*4);
  ushort_t* hall   = (ushort_t*)alloc((size_t)2048*1024*2);
  float* pmax      = (float*)alloc((size_t)2048*VTILES*4);
  float* psum      = (float*)alloc((size_t)2048*VTILES*4);
  float* row_loss  = (float*)alloc((size_t)2048*4);

  hipLaunchKernelGGL(k_transpose_cvt, dim3(64, 8),   dim3(256), 0, stream, Wx,     WcatT,  4096, 2560, 0);
  hipLaunchKernelGGL(k_transpose_cvt, dim3(64, 16),  dim3(256), 0, stream, Wh,     WcatT,  4096, 2560, 512);
  hipLaunchKernelGGL(k_transpose_cvt, dim3(64, 16),  dim3(256), 0, stream, Wattn,  WcatT,  4096, 2560, 1536);
  hipLaunchKernelGGL(k_transpose_cvt, dim3(500, 16), dim3(256), 0, stream, W_out,  WoutT,  32000, 1024, 0);
  hipLaunchKernelGGL(k_transpose_cvt, dim3(16, 16),  dim3(256), 0, stream, W_proj, WprojT, 1024, 1024, 0);
  hipLaunchKernelGGL(k_featT, dim3(64), dim3(256), 0, stream, features, fBT);
  hipLaunchKernelGGL(k_embed, dim3(1024), dim3(256), 0, stream, captions, W_embed, xb);
  hipLaunchKernelGGL(k_projmm, dim3(16, 16), dim3(256), 0, stream, WprojT, fBT, b_proj, A_flat, Abt, hbuf);
  hipLaunchKernelGGL(k_pmm, dim3(64, 16), dim3(256), 0, stream, WcatT, Abt, P3);
  hipLaunchKernelGGL(k_xmm, dim3(64, 32), dim3(256), 0, stream, WcatT, xb, xpre);

  for (int i = 0; i <= 32; ++i){
    const float* sp_rd = spbuf + ((i+1)&1)*4096;
    float*       sp_wr = spbuf + (i&1)*4096;
    hipLaunchKernelGGL(k_gate, dim3(256), dim3(256), 0, stream, i, xpre, a_part, b, P3,
                       A_flat, hbuf, cbuf, sp_rd, sp_wr, hbf, hall);
    if (i < 32)
      hipLaunchKernelGGL(k_mm, dim3(64, 8), dim3(256), 0, stream, WcatT, hbf, a_part);
  }

  hipLaunchKernelGGL(k_score, dim3(2000), dim3(512), 0, stream, WoutT, hall, b_out, pmax, psum);
  hipLaunchKernelGGL(k_nll, dim3(512), dim3(256), 0, stream, hall, WoutT, b_out, captions, pmax, psum, row_loss);
  hipLaunchKernelGGL(k_final, dim3(1), dim3(256), 0, stream, row_loss, out);
}